// Round 7
// baseline (213.969 us; speedup 1.0000x reference)
//
#include <hip/hip_runtime.h>

// Problem constants (from reference setup_inputs)
#define BB 4
#define CC 64
#define HH 56
#define WW 56
#define HW (HH*WW)

typedef unsigned short u16;
typedef unsigned int u32;
typedef __attribute__((ext_vector_type(8))) short bf16x8;
typedef __attribute__((ext_vector_type(4))) float f32x4;

__device__ __forceinline__ u16 f2bf(float f) {
    union { float f; unsigned u; } c; c.f = f;
    unsigned u = c.u;
    u = (u + 0x7FFFu + ((u >> 16) & 1u)) >> 16;   // RNE
    return (u16)u;
}
__device__ __forceinline__ float lo_f(u32 u) {   // bf16 pair -> lo fp32
    union { unsigned u; float f; } c; c.u = u << 16; return c.f;
}
__device__ __forceinline__ float hi_f(u32 u) {   // bf16 pair -> hi fp32
    union { unsigned u; float f; } c; c.u = u & 0xffff0000u; return c.f;
}

// global_load_lds: per-lane global src, wave-uniform LDS base + lane*16.
typedef const __attribute__((address_space(1))) unsigned int guint;
typedef __attribute__((address_space(3))) unsigned int luint;
__device__ __forceinline__ void gl_lds16(const void* g, void* l) {
    __builtin_amdgcn_global_load_lds((guint*)g, (luint*)l, 16, 0, 0);
}

// Padded image geometry
#define W1P 60            // conv1 input pad 2: (56+4)
#define PB1 3600          // 60*60
#define W2P 74            // conv2 input pad 9: (56+18)
#define PB2 5476          // 74*74

// ---------------------------------------------------------------------------
// Fused prep: input transpose -> padded xTp, weight reshape/cast (w2t now
// stored PRE-XOR-SWIZZLED: element ic of row n sits at slot ((ic>>3)+n)&7,
// so conv's linear global_load_lds deposit reproduces the conflict-free
// LDS layout), and zeroing of xTp / a1Tp padding borders.
// ---------------------------------------------------------------------------
#define R1 102400
#define R2 401408
#define R3 4096
#define R4 1600
#define R5 3136
#define R6z (BB*PB1*8)    // xTp border-zero candidates (16B each)
#define R7z (BB*PB2*8)    // a1Tp border-zero candidates
#define TGRID (BB*(HW/64))          // 196
#define PREPN (R1+R2+R3+R4+R5+R6z+R7z)
__global__ __launch_bounds__(256)
void prep_tr_kernel(const float* __restrict__ x,
                    const float* __restrict__ ow1, const float* __restrict__ ow2,
                    const float* __restrict__ pw,  const float* __restrict__ dw1,
                    const float* __restrict__ dw2,
                    u16* __restrict__ xTp, u16* __restrict__ a1Tp,
                    u16* __restrict__ w2t1, u16* __restrict__ w2t2,
                    u16* __restrict__ pwT, float* __restrict__ dwT1,
                    float* __restrict__ dwT2) {
    __shared__ u16 tile[64][72];
    const int t = threadIdx.x;
    if (blockIdx.x < TGRID) {
        const int blk = blockIdx.x;
        const int b   = blk / (HW/64);
        const int p0  = (blk % (HW/64))*64;
        const int px  = t & 63, icq = t >> 6;
        const float* ip = x + ((size_t)b*CC + icq*16)*HW + p0 + px;
        #pragma unroll
        for (int i = 0; i < 16; ++i)
            tile[px][icq*16 + i] = f2bf(ip[(size_t)i*HW]);
        __syncthreads();
        const int px2 = t >> 2, g = t & 3;
        const int p = p0 + px2;
        const int y = p / WW, xw = p % WW;
        u16* op = xTp + ((size_t)b*PB1 + (y+2)*W1P + (xw+2))*64 + g*16;
        const uint4* s = (const uint4*)&tile[px2][g*16];
        ((uint4*)op)[0] = s[0];
        ((uint4*)op)[1] = s[1];
        return;
    }
    const int i = (blockIdx.x - TGRID)*256 + t;
    if (i < R1) {
        const int ic = i & 63, n = (i >> 6) & 63, tap = i >> 12;
        const int sw = ((((ic >> 3) + n) & 7) << 3) | (ic & 7);
        w2t1[(i & ~63) | sw] = f2bf((n < 50) ? ow1[((size_t)n*64 + ic)*25 + tap] : 0.f);
    } else if (i < R1+R2) {
        const int j = i - R1;
        const int ic = j & 63, n = (j >> 6) & 127, tap = j >> 13;
        const int sw = ((((ic >> 3) + n) & 7) << 3) | (ic & 7);
        w2t2[(j & ~63) | sw] = f2bf((n < 98) ? ow2[((size_t)n*64 + ic)*49 + tap] : 0.f);
    } else if (i < R1+R2+R3) {
        const int j = i - (R1+R2);
        pwT[j] = f2bf(pw[j]);
    } else if (i < R1+R2+R3+R4) {
        const int j = i - (R1+R2+R3);
        const int c = j & 63, k = j >> 6;
        dwT1[j] = dw1[c*25 + k];
    } else if (i < R1+R2+R3+R4+R5) {
        const int j = i - (R1+R2+R3+R4);
        const int c = j & 63, k = j >> 6;
        dwT2[j] = dw2[c*49 + k];
    } else if (i < R1+R2+R3+R4+R5+R6z) {
        const int j = i - (R1+R2+R3+R4+R5);
        const int c8 = j & 7, q = j >> 3;
        const int px = q % PB1, bz = q / PB1;
        const int y = px / W1P, xx = px % W1P;
        if (y < 2 || y >= 58 || xx < 2 || xx >= 58)
            *(uint4*)(xTp + ((size_t)bz*PB1 + px)*64 + c8*8) = make_uint4(0,0,0,0);
    } else if (i < PREPN) {
        const int j = i - (R1+R2+R3+R4+R5+R6z);
        const int c8 = j & 7, q = j >> 3;
        const int px = q % PB2, bz = q / PB2;
        const int y = px / W2P, xx = px % W2P;
        if (y < 9 || y >= 65 || xx < 9 || xx >= 65)
            *(uint4*)(a1Tp + ((size_t)bz*PB2 + px)*64 + c8*8) = make_uint4(0,0,0,0);
    }
}

// ---------------------------------------------------------------------------
// Barrier-light MFMA conv: A DIRECT from padded global (the [pixel][64ch]
// layout IS the MFMA A-fragment layout: lane(r,quad) reads 16B at
// pixel(r)*64 + quad*8 (+32 for k-hi)), only B goes through LDS.
// B staged one kernel-row (K taps, K*2KB) at a time, double-buffered via
// global_load_lds from pre-swizzled w2t -> K barriers total (was K*K).
// Block = 256 thr = 64 px x 16 n. conv1 grid (196,4)=12.3 waves/CU,
// conv2 grid (196,7)=21.4 waves/CU (28KB LDS -> 5 blk/CU); nt0=7 padding
// tile never launched. Tap order and av0/av1 order unchanged -> bit-identical.
// ---------------------------------------------------------------------------
template<int K, int DIL, int PAD, int COUT, int NP, int NPAD>
__global__ __launch_bounds__(256, 4)
void conv_mfma_ad_kernel(const u16* __restrict__ inTp, const u16* __restrict__ w2t,
                         const float* __restrict__ bias, float* __restrict__ out) {
    constexpr int WP = WW + 2*PAD;
    __shared__ u16 Bb[2][K*16*64];

    const int nm   = HW/64;                       // 49
    const int b    = blockIdx.x / nm;
    const int p0   = (blockIdx.x % nm)*64;
    const int nt0  = blockIdx.y;
    const int t    = threadIdx.x;
    const int wave = t >> 6;
    const int lane = t & 63;
    const int r = lane & 15, quad = lane >> 4;

    // A: per-lane fixed pixel row, direct global
    const int mpx = p0 + wave*16 + r;
    const int py = mpx / WW, px = mpx % WW;
    const u16* aptr = inTp + ((size_t)b*((HH+2*PAD)*WP) + (size_t)(py+PAD)*WP + (px+PAD))*64 + quad*8;

    // B staging src: rows nt0*16..+16 of each tap (pre-swizzled)
    const u16* wsrc = w2t + (size_t)nt0*16*64 + lane*8;

    const int b0s = ((quad     + r) & 7)*8;
    const int b1s = ((quad + 4 + r) & 7)*8;

    f32x4 acc = (f32x4){0.f,0.f,0.f,0.f};

    auto STAGE = [&](int c) {
        u16* dst = &Bb[c & 1][0];
        for (int s = wave; s < 2*K; s += 4) {
            const int tap = c*K + (s >> 1);
            gl_lds16(wsrc + (size_t)tap*NP*64 + (s & 1)*512,
                     dst + (s >> 1)*1024 + (s & 1)*512);
        }
    };

    STAGE(0);
    __syncthreads();

    for (int c = 0; c < K; ++c) {
        if (c + 1 < K) STAGE(c + 1);
        const u16* Bq = &Bb[c & 1][0];
        const int arow0 = (c*DIL - PAD)*WP*64;
        #pragma unroll
        for (int kk = 0; kk < K; ++kk) {
            const int aoff = arow0 + (kk*DIL - PAD)*64;
            const bf16x8 av0 = *(const bf16x8*)(aptr + aoff);
            const bf16x8 av1 = *(const bf16x8*)(aptr + aoff + 32);
            const u16* Brow = Bq + kk*1024 + r*64;
            const bf16x8 bv0 = *(const bf16x8*)(Brow + b0s);
            const bf16x8 bv1 = *(const bf16x8*)(Brow + b1s);
            acc = __builtin_amdgcn_mfma_f32_16x16x32_bf16(av0, bv0, acc, 0, 0, 0);
            acc = __builtin_amdgcn_mfma_f32_16x16x32_bf16(av1, bv1, acc, 0, 0, 0);
        }
        __syncthreads();
    }

    const int n = nt0*16 + r;
    if (n < COUT) {
        const float bv = bias[n];
        float* op = out + ((size_t)b*HW + p0 + wave*16 + quad*4)*NPAD + n;
        #pragma unroll
        for (int r2 = 0; r2 < 4; ++r2) op[(size_t)r2*NPAD] = acc[r2] + bv;
    }
}

// ---------------------------------------------------------------------------
// Two-phase deform, 2 channels/lane, R5 software-pipelined tap loop
// (measured-best; 8 px/block, grid 1568, 24 waves/CU, single barrier).
// Padded input (IP/IWP/IPB) and padded output (OP/OWP/OPB).
// ---------------------------------------------------------------------------
template<int K, int DIL, int PAD, int NPAD,
         int IP, int IWP, int IPB, int OP, int OWP, int OPB>
__global__ __launch_bounds__(256)
void deform_cl_kernel(const u16* __restrict__ inT, const float* __restrict__ offT,
                      const float* __restrict__ dwT, u16* __restrict__ outT) {
    constexpr int KK = K*K;
    __shared__ float4 swt[8][KK];
    __shared__ int4   sat[8][KK];
    __shared__ float  sdw[KK*64];

    const int t = threadIdx.x;
    const int nb8 = (BB*HW/8) >> 3;               // 196
    const int blk0 = blockIdx.x;
    const int blk = (blk0 & 7)*nb8 + (blk0 >> 3); // XCD-contiguous pixels
    const int p0 = blk*8;
    const int b  = p0 / HW;                       // 8 | HW -> same batch
    const int pl0 = p0 - b*HW;

    for (int i = t; i < KK*64; i += 256) sdw[i] = dwT[i];

    for (int i = t; i < 8*KK; i += 256) {
        const int pix = i / KK, k = i - pix*KK;
        const int pl  = pl0 + pix;
        const int h = pl / WW, w = pl % WW;
        const float* orow = offT + ((size_t)b*HW + pl)*NPAD;
        const float dy = orow[2*k];
        const float dx = orow[2*k+1];
        const float py = (float)(h + (k/K)*DIL - PAD) + dy;
        const float px = (float)(w + (k%K)*DIL - PAD) + dx;
        const float y0f = floorf(py), x0f = floorf(px);
        const float wy1 = py - y0f,  wx1 = px - x0f;
        const float wy0 = 1.f - wy1, wx0 = 1.f - wx1;
        const int y0 = (int)y0f, x0 = (int)x0f;

        const int y0c = min(max(y0,   0), HH-1);
        const int y1c = min(max(y0+1, 0), HH-1);
        const int x0c = min(max(x0,   0), WW-1);
        const int x1c = min(max(x0+1, 0), WW-1);
        const float gy0 = wy0 * ((y0   >= 0 && y0   < HH) ? 1.f : 0.f);
        const float gy1 = wy1 * ((y0+1 >= 0 && y0+1 < HH) ? 1.f : 0.f);
        const float gx0 = wx0 * ((x0   >= 0 && x0   < WW) ? 1.f : 0.f);
        const float gx1 = wx1 * ((x0+1 >= 0 && x0+1 < WW) ? 1.f : 0.f);

        swt[pix][k] = make_float4(gy0*gx0, gy0*gx1, gy1*gx0, gy1*gx1);
        const int r0 = (y0c + IP)*IWP, r1 = (y1c + IP)*IWP;
        sat[pix][k] = make_int4((r0 + x0c + IP) << 7, (r0 + x1c + IP) << 7,
                                (r1 + x0c + IP) << 7, (r1 + x1c + IP) << 7);
    }
    __syncthreads();

    const int wave = t >> 6, lane = t & 63;
    const int pixl = 2*wave + (lane >> 5);        // 0..7 (half-wave = pixel)
    const int chp  = lane & 31;                   // channel pair 0..31
    const char* ib = (const char*)(inT + (size_t)b*IPB*64) + chp*4;

    float accx = 0.f, accy = 0.f;

    int4   av[3];
    float4 wv[2];
    float2 dv[2];
    u32 c00[2], c01[2], c10[2], c11[2];

    av[0] = sat[pixl][0];
    if (KK > 1) av[1] = sat[pixl][1];
    wv[0] = swt[pixl][0];
    dv[0] = *(const float2*)&sdw[2*chp];
    c00[0] = *(const u32*)(ib + av[0].x);
    c01[0] = *(const u32*)(ib + av[0].y);
    c10[0] = *(const u32*)(ib + av[0].z);
    c11[0] = *(const u32*)(ib + av[0].w);

    #pragma unroll
    for (int k = 0; k < KK; ++k) {
        const int kn = k + 1;
        if (kn + 1 < KK) av[(kn+1)%3] = sat[pixl][kn+1];
        if (kn < KK) {
            wv[kn&1] = swt[pixl][kn];
            dv[kn&1] = *(const float2*)&sdw[kn*64 + 2*chp];
            const int4 a = av[kn%3];
            c00[kn&1] = *(const u32*)(ib + a.x);
            c01[kn&1] = *(const u32*)(ib + a.y);
            c10[kn&1] = *(const u32*)(ib + a.z);
            c11[kn&1] = *(const u32*)(ib + a.w);
        }
        const float4 w = wv[k&1];
        const u32 u00 = c00[k&1], u01 = c01[k&1], u10 = c10[k&1], u11 = c11[k&1];
        const float sx = lo_f(u00)*w.x + lo_f(u01)*w.y + lo_f(u10)*w.z + lo_f(u11)*w.w;
        const float sy = hi_f(u00)*w.x + hi_f(u01)*w.y + hi_f(u10)*w.z + hi_f(u11)*w.w;
        const float2 d = dv[k&1];
        accx += sx * d.x;
        accy += sy * d.y;
    }

    const int oy = (pl0 + pixl) / WW, ox = (pl0 + pixl) % WW;
    const int opx = (oy + OP)*OWP + (ox + OP);
    const u32 o = (u32)f2bf(accx) | ((u32)f2bf(accy) << 16);
    *(u32*)((char*)outT + ((size_t)b*OPB + opx)*128 + chp*4) = o;
}

// ---------------------------------------------------------------------------
// Pointwise 1x1 via MFMA + fused residual multiply; wave = 16 px x 1 n-tile.
// ---------------------------------------------------------------------------
__global__ __launch_bounds__(256)
void pw_mfma_kernel(const u16* __restrict__ a2T, const u16* __restrict__ pwT,
                    const float* __restrict__ pb, const float* __restrict__ x,
                    float* __restrict__ out) {
    const int nm = HW/64;
    const int b  = blockIdx.x / nm;
    const int p0 = (blockIdx.x % nm)*64 + (threadIdx.x >> 6)*16;
    const int nt = blockIdx.y;
    const int lane = threadIdx.x & 63;
    const int r = lane & 15, quad = lane >> 4;

    const u16* ap = a2T + ((size_t)b*HW + p0 + r)*64 + quad*8;
    f32x4 acc = (f32x4){0.f,0.f,0.f,0.f};
    #pragma unroll
    for (int ks = 0; ks < 2; ++ks) {
        const bf16x8 av = *(const bf16x8*)(ap + ks*32);
        const bf16x8 bv = *(const bf16x8*)(pwT + ((size_t)(nt*16 + r))*64 + ks*32 + quad*8);
        acc = __builtin_amdgcn_mfma_f32_16x16x32_bf16(av, bv, acc, 0, 0, 0);
    }

    const int n = nt*16 + r;
    const float bv = pb[n];
    const size_t base = ((size_t)b*CC + n)*HW + p0 + quad*4;
    #pragma unroll
    for (int r2 = 0; r2 < 4; ++r2)
        out[base + r2] = x[base + r2] * (acc[r2] + bv);
}

// ======================= fallback fp32 kernels (low ws) =====================
template<int K, int DIL, int PAD, int COUT, int OCB>
__global__ __launch_bounds__(256)
void off_conv_sg_kernel(const float* __restrict__ in, const float* __restrict__ wgt,
                        const float* __restrict__ bias, float* __restrict__ out) {
    constexpr int KK = K*K;
    const int nOB = COUT / OCB;
    const int b   = blockIdx.x / nOB;
    const int oc0 = (blockIdx.x % nOB) * OCB;
    const int x   = threadIdx.x;
    const int h   = blockIdx.y*4 + threadIdx.y;

    float acc[OCB];
    #pragma unroll
    for (int o = 0; o < OCB; ++o) acc[o] = bias[oc0+o];

    const float* inb = in + (size_t)b*CC*HW;
    const float* wb  = wgt + (size_t)oc0*CC*KK;

    for (int ic = 0; ic < CC; ++ic) {
        const float* inp = inb + ic*HW;
        const float* wp  = wb + ic*KK;
        #pragma unroll
        for (int ky = 0; ky < K; ++ky) {
            const int  y  = h + ky*DIL - PAD;
            const bool yv = (y >= 0) && (y < HH);
            const int  yc = yv ? y : 0;
            const float* row = inp + yc*WW;
            #pragma unroll
            for (int kx = 0; kx < K; ++kx) {
                const int  xx = x + kx*DIL - PAD;
                const bool v  = yv && (xx >= 0) && (xx < WW);
                const int  xc = (xx < 0) ? 0 : ((xx >= WW) ? (WW-1) : xx);
                float val = row[xc];
                val = v ? val : 0.f;
                const int t = ky*K + kx;
                #pragma unroll
                for (int o = 0; o < OCB; ++o)
                    acc[o] += wp[(size_t)o*CC*KK + t] * val;
            }
        }
    }

    if (x >= WW) return;
    #pragma unroll
    for (int o = 0; o < OCB; ++o)
        out[((size_t)b*COUT + oc0 + o)*HW + h*WW + x] = acc[o];
}

template<int K, int DIL, int PAD>
__global__ __launch_bounds__(64)
void deform_dw_full_kernel(const float* __restrict__ in, const float* __restrict__ off,
                           const float* __restrict__ dw, float* __restrict__ out) {
    constexpr int KK = K*K;
    const int idx = blockIdx.x*64 + threadIdx.x;
    const int x = idx % WW;
    const int h = (idx / WW) % HH;
    const int c = (idx / HW) % CC;
    const int b = idx / (CC*HW);

    const float* inp  = in  + ((size_t)b*CC + c)*HW;
    const float* offp = off + (size_t)b*(2*KK)*HW + h*WW + x;
    const float* dwp  = dw  + c*KK;

    float acc = 0.f;
    #pragma unroll 7
    for (int k = 0; k < KK; ++k) {
        const float dy = offp[(2*k  )*HW];
        const float dx = offp[(2*k+1)*HW];
        const float py = (float)(h + (k/K)*DIL - PAD) + dy;
        const float px = (float)(x + (k%K)*DIL - PAD) + dx;
        const float y0f = floorf(py), x0f = floorf(px);
        const float wy1 = py - y0f,  wx1 = px - x0f;
        const float wy0 = 1.f - wy1, wx0 = 1.f - wx1;
        const int y0 = (int)y0f, x0 = (int)x0f;

        const int y0c = min(max(y0,   0), HH-1);
        const int y1c = min(max(y0+1, 0), HH-1);
        const int x0c = min(max(x0,   0), WW-1);
        const int x1c = min(max(x0+1, 0), WW-1);
        const float my0 = (y0   >= 0 && y0   < HH) ? 1.f : 0.f;
        const float my1 = (y0+1 >= 0 && y0+1 < HH) ? 1.f : 0.f;
        const float mx0 = (x0   >= 0 && x0   < WW) ? 1.f : 0.f;
        const float mx1 = (x0+1 >= 0 && x0+1 < WW) ? 1.f : 0.f;

        const float v00 = inp[y0c*WW + x0c];
        const float v01 = inp[y0c*WW + x1c];
        const float v10 = inp[y1c*WW + x0c];
        const float v11 = inp[y1c*WW + x1c];

        const float gx0 = wx0*mx0, gx1 = wx1*mx1;
        const float s = (v00*gx0 + v01*gx1) * (wy0*my0)
                      + (v10*gx0 + v11*gx1) * (wy1*my1);
        acc += s * dwp[k];
    }
    out[idx] = acc;
}

__global__ __launch_bounds__(256)
void pw_mul_kernel(const float* __restrict__ x, const float* __restrict__ a2,
                   const float* __restrict__ pw, const float* __restrict__ pb,
                   float* __restrict__ out) {
    constexpr int HW4 = HW/4;
    const int t = blockIdx.x*256 + threadIdx.x;
    if (t >= BB*CC*HW4) return;
    const int sp4 = t % HW4;
    const int oc  = (t / HW4) % CC;
    const int b   = t / (CC*HW4);

    const float4* ap = (const float4*)(a2 + (size_t)b*CC*HW) + sp4;
    const float4* wp4 = (const float4*)(pw + oc*CC);
    const float pbv = pb[oc];
    float4 acc = make_float4(pbv, pbv, pbv, pbv);
    #pragma unroll 4
    for (int ic4 = 0; ic4 < CC/4; ++ic4) {
        const float4 w = wp4[ic4];
        float4 a0 = ap[(ic4*4+0)*HW4];
        float4 a1 = ap[(ic4*4+1)*HW4];
        float4 a2v = ap[(ic4*4+2)*HW4];
        float4 a3 = ap[(ic4*4+3)*HW4];
        acc.x += w.x*a0.x + w.y*a1.x + w.z*a2v.x + w.w*a3.x;
        acc.y += w.x*a0.y + w.y*a1.y + w.z*a2v.y + w.w*a3.y;
        acc.z += w.x*a0.z + w.y*a1.z + w.z*a2v.z + w.w*a3.z;
        acc.w += w.x*a0.w + w.y*a1.w + w.z*a2v.w + w.w*a3.w;
    }
    const float4 xv = ((const float4*)x)[t];
    float4 r;
    r.x = xv.x*acc.x; r.y = xv.y*acc.y; r.z = xv.z*acc.z; r.w = xv.w*acc.w;
    ((float4*)out)[t] = r;
}

extern "C" void kernel_launch(void* const* d_in, const int* in_sizes, int n_in,
                              void* d_out, int out_size, void* d_ws, size_t ws_size,
                              hipStream_t stream) {
    const float* x      = (const float*)d_in[0];
    const float* off_w1 = (const float*)d_in[1];
    const float* off_b1 = (const float*)d_in[2];
    const float* dw_w1  = (const float*)d_in[3];
    const float* off_w2 = (const float*)d_in[4];
    const float* off_b2 = (const float*)d_in[5];
    const float* dw_w2  = (const float*)d_in[6];
    const float* pw_w   = (const float*)d_in[7];
    const float* pw_b   = (const float*)d_in[8];
    float* out = (float*)d_out;

    const size_t nF    = (size_t)BB*CC*HW;
    const size_t attnB = nF*sizeof(float);
    const size_t off2B = (size_t)BB*98*HW*sizeof(float);   // fallback layout
    const size_t offTB = (size_t)BB*HW*112*sizeof(float);  // transposed offsets
    const size_t chB   = (size_t)BB*HW*64*sizeof(u16);
    const size_t xpB   = (size_t)BB*PB1*64*sizeof(u16);    // padded xTp
    const size_t a1pB  = (size_t)BB*PB2*64*sizeof(u16);    // padded a1Tp
    char* ws = (char*)d_ws;

    const int n    = (int)nF;
    const int dbl  = n/64;
    const int pbl  = (n/4 + 255)/256;
    dim3 cblk(64,4);
    dim3 rgrd1(BB*(50/5), HH/4);
    dim3 rgrd2(BB*(98/7), HH/4);
    dim3 cgrd1(TGRID, 4);                    // conv1: 4 x 16-n tiles
    dim3 cgrd2(TGRID, 7);                    // conv2: 7 x 16-n tiles (112 real)
    dim3 pgrd(TGRID, 4);                     // pw
    const int dgrid = BB*HW/8;               // 1568 (8 pixels per block)

    const size_t oOFF  = 0;
    const size_t oXTP  = oOFF  + offTB;
    const size_t oA1TP = oXTP  + xpB;
    const size_t oA2T  = oA1TP + a1pB;
    const size_t oW1   = oA2T  + chB;
    const size_t oW2   = oW1   + (size_t)R1*2;
    const size_t oPWT  = oW2   + (size_t)R2*2;
    const size_t oDW1  = oPWT  + (size_t)R3*2;
    const size_t oDW2  = oDW1  + (size_t)R4*4;
    const size_t TOT   = oDW2  + (size_t)R5*4;   // ~12.9 MB

    if (ws_size >= TOT) {
        float* off_buf = (float*)(ws + oOFF);
        u16*   xTp     = (u16*)(ws + oXTP);
        u16*   a1Tp    = (u16*)(ws + oA1TP);
        u16*   a2T     = (u16*)(ws + oA2T);
        u16*   w2t1    = (u16*)(ws + oW1);
        u16*   w2t2    = (u16*)(ws + oW2);
        u16*   pwT     = (u16*)(ws + oPWT);
        float* dwT1    = (float*)(ws + oDW1);
        float* dwT2    = (float*)(ws + oDW2);

        prep_tr_kernel<<<TGRID + (PREPN+255)/256, 256, 0, stream>>>(
            x, off_w1, off_w2, pw_w, dw_w1, dw_w2,
            xTp, a1Tp, w2t1, w2t2, pwT, dwT1, dwT2);

        conv_mfma_ad_kernel<5,1,2,50,64,64><<<cgrd1, 256, 0, stream>>>(xTp, w2t1, off_b1, off_buf);
        deform_cl_kernel<5,1,2,64, 2,W1P,PB1, 9,W2P,PB2><<<dgrid, 256, 0, stream>>>(xTp, off_buf, dwT1, a1Tp);

        conv_mfma_ad_kernel<7,3,9,98,128,112><<<cgrd2, 256, 0, stream>>>(a1Tp, w2t2, off_b2, off_buf);
        deform_cl_kernel<7,3,9,112, 9,W2P,PB2, 0,WW,HW><<<dgrid, 256, 0, stream>>>(a1Tp, off_buf, dwT2, a2T);

        pw_mfma_kernel<<<pgrd, 256, 0, stream>>>(a2T, pwT, pw_b, x, out);
    } else if (ws_size >= off2B + attnB) {
        float* off_buf = (float*)ws;
        float* attn1   = (float*)d_out;
        float* attn2   = (float*)(ws + off2B);
        off_conv_sg_kernel<5,1,2,50,5><<<rgrd1, cblk, 0, stream>>>(x, off_w1, off_b1, off_buf);
        deform_dw_full_kernel<5,1,2><<<dbl, 64, 0, stream>>>(x, off_buf, dw_w1, attn1);
        off_conv_sg_kernel<7,3,9,98,7><<<rgrd2, cblk, 0, stream>>>(attn1, off_w2, off_b2, off_buf);
        deform_dw_full_kernel<7,3,9><<<dbl, 64, 0, stream>>>(attn1, off_buf, dw_w2, attn2);
        pw_mul_kernel<<<pbl, 256, 0, stream>>>(x, attn2, pw_w, pw_b, out);
    } else {
        float* attn1 = (float*)d_out;
        float* attn2 = (float*)ws;
        float* off1  = (float*)ws;
        off_conv_sg_kernel<5,1,2,50,5><<<rgrd1, cblk, 0, stream>>>(x, off_w1, off_b1, off1);
        deform_dw_full_kernel<5,1,2><<<dbl, 64, 0, stream>>>(x, off1, dw_w1, attn1);
        float* off2 = (float*)(ws + attnB);
        off_conv_sg_kernel<7,3,9,98,7><<<rgrd2, cblk, 0, stream>>>(attn1, off_w2, off_b2, off2);
        deform_dw_full_kernel<7,3,9><<<dbl, 64, 0, stream>>>(attn1, off2, dw_w2, attn2);
        pw_mul_kernel<<<pbl, 256, 0, stream>>>(x, attn2, pw_w, pw_b, out);
    }
}

// Round 9
// 160.890 us; speedup vs baseline: 1.3299x; 1.3299x over previous
//
#include <hip/hip_runtime.h>

// Problem constants (from reference setup_inputs)
#define BB 4
#define CC 64
#define HH 56
#define WW 56
#define HW (HH*WW)

typedef unsigned short u16;
typedef unsigned int u32;
typedef __attribute__((ext_vector_type(8))) short bf16x8;
typedef __attribute__((ext_vector_type(4))) float f32x4;

__device__ __forceinline__ u16 f2bf(float f) {
    union { float f; unsigned u; } c; c.f = f;
    unsigned u = c.u;
    u = (u + 0x7FFFu + ((u >> 16) & 1u)) >> 16;   // RNE
    return (u16)u;
}
__device__ __forceinline__ float lo_f(u32 u) {   // bf16 pair -> lo fp32
    union { unsigned u; float f; } c; c.u = u << 16; return c.f;
}
__device__ __forceinline__ float hi_f(u32 u) {   // bf16 pair -> hi fp32
    union { unsigned u; float f; } c; c.u = u & 0xffff0000u; return c.f;
}

// ---------------------------------------------------------------------------
// Fused prep + input transpose in ONE launch (R5 baseline).
// ---------------------------------------------------------------------------
#define R1 102400
#define R2 401408
#define R3 4096
#define R4 1600
#define R5 3136
#define TGRID (BB*(HW/64))          // 196
#define PREPN (R1+R2+R3+R4+R5)
__global__ __launch_bounds__(256)
void prep_tr_kernel(const float* __restrict__ x,
                    const float* __restrict__ ow1, const float* __restrict__ ow2,
                    const float* __restrict__ pw,  const float* __restrict__ dw1,
                    const float* __restrict__ dw2,
                    u16* __restrict__ xT,
                    u16* __restrict__ w2t1, u16* __restrict__ w2t2,
                    u16* __restrict__ pwT, float* __restrict__ dwT1,
                    float* __restrict__ dwT2) {
    __shared__ u16 tile[64][72];
    const int t = threadIdx.x;
    if (blockIdx.x < TGRID) {
        const int blk = blockIdx.x;
        const int b   = blk / (HW/64);
        const int p0  = (blk % (HW/64))*64;
        const int px  = t & 63, icq = t >> 6;
        const float* ip = x + ((size_t)b*CC + icq*16)*HW + p0 + px;
        #pragma unroll
        for (int i = 0; i < 16; ++i)
            tile[px][icq*16 + i] = f2bf(ip[(size_t)i*HW]);
        __syncthreads();
        const int px2 = t >> 2, g = t & 3;
        u16* op = xT + ((size_t)b*HW + p0 + px2)*64 + g*16;
        const uint4* s = (const uint4*)&tile[px2][g*16];
        ((uint4*)op)[0] = s[0];
        ((uint4*)op)[1] = s[1];
        return;
    }
    const int i = (blockIdx.x - TGRID)*256 + t;
    if (i < R1) {
        const int ic = i & 63, n = (i >> 6) & 63, tap = i >> 12;
        w2t1[i] = f2bf((n < 50) ? ow1[((size_t)n*64 + ic)*25 + tap] : 0.f);
    } else if (i < R1+R2) {
        const int j = i - R1;
        const int ic = j & 63, n = (j >> 6) & 127, tap = j >> 13;
        w2t2[j] = f2bf((n < 98) ? ow2[((size_t)n*64 + ic)*49 + tap] : 0.f);
    } else if (i < R1+R2+R3) {
        const int j = i - (R1+R2);
        pwT[j] = f2bf(pw[j]);
    } else if (i < R1+R2+R3+R4) {
        const int j = i - (R1+R2+R3);
        const int c = j & 63, k = j >> 6;
        dwT1[j] = dw1[c*25 + k];
    } else if (i < R1+R2+R3+R4+R5) {
        const int j = i - (R1+R2+R3+R4);
        const int c = j & 63, k = j >> 6;
        dwT2[j] = dw2[c*49 + k];
    }
}

__device__ __forceinline__ uint4 selz(bool v, uint4 a) {
    const uint4 z = make_uint4(0,0,0,0);
    return v ? a : z;
}

// ---------------------------------------------------------------------------
// LDS-staged MFMA implicit-GEMM conv, 2 TAPS PER BARRIER PHASE.
// Same staging/swizzle/MFMA math as the R5 baseline (A+B through LDS,
// double-buffered, tap order preserved -> bit-identical), but each phase
// stages TPB=2 taps and runs 2 taps of MFMA per __syncthreads(), halving
// the per-barrier vmcnt-drain count (conv1 25->13, conv2 49->25).
// conv1 runs NTW=1 x 4 y-tiles (3.06 blocks/CU, was 1.53 grid-starved).
// ---------------------------------------------------------------------------
template<int K, int DIL, int PAD, int COUT, int NP, int NPAD, int NTW>
__global__ __launch_bounds__(256, 4)
void conv_mfma_lds_kernel(const u16* __restrict__ xT, const u16* __restrict__ w2t,
                          const float* __restrict__ bias, float* __restrict__ out) {
    constexpr int KK = K*K;
    constexpr int TPB = 2;
    constexpr int NPH = (KK + TPB - 1) / TPB;
    constexpr int BROWS = 16*NTW;
    __shared__ u16 Ab[2][TPB*64*64];
    __shared__ u16 Bb[2][TPB*BROWS*64];

    const int nm   = HW/64;                       // 49
    const int b    = blockIdx.x / nm;
    const int p0   = (blockIdx.x % nm)*64;
    const int nt0  = blockIdx.y;
    const int t    = threadIdx.x;
    const int wave = t >> 6;
    const int lane = t & 63;

    const int spx = t >> 3;                       // 0..31
    const int sc  = t & 7;                        // chunk 0..7
    const int pA  = p0 + spx;
    const int pB  = p0 + spx + 32;
    const int pyA = pA / WW, pxA = pA % WW;
    const int pyB = pB / WW, pxB = pB % WW;
    const u16* xb = xT + (size_t)b*HW*64;
    const int sslotA = ((sc + spx) & 7)*8;
    const int bn  = t >> 3;                       // 0..31
    const int bslot = ((sc + bn) & 7)*8;
    const u16* wbase = w2t + (size_t)nt0*BROWS*64;

    const int r = lane & 15, quad = lane >> 4;
    const int mloc = wave*16 + r;
    const int arow = mloc*64;
    const int a0s = ((quad     + mloc) & 7)*8;
    const int a1s = ((quad + 4 + mloc) & 7)*8;
    const int b0s = ((quad     + r) & 7)*8;
    const int b1s = ((quad + 4 + r) & 7)*8;

    f32x4 acc[NTW];
    #pragma unroll
    for (int h = 0; h < NTW; ++h) acc[h] = (f32x4){0.f,0.f,0.f,0.f};
    const uint4 z4 = make_uint4(0,0,0,0);

    auto LD = [&](int tap, uint4& a0, uint4& a1, bool& va, bool& vb, uint4& bb) {
        const int dyy = (tap/K)*DIL - PAD;
        const int dxx = (tap%K)*DIL - PAD;
        const int off = dyy*WW + dxx;
        {
            const int yy = pyA + dyy, xx = pxA + dxx;
            va = ((unsigned)yy < (unsigned)HH) && ((unsigned)xx < (unsigned)WW);
            a0 = *(const uint4*)(xb + (size_t)(va ? (pA + off) : 0)*64 + sc*8);
        }
        {
            const int yy = pyB + dyy, xx = pxB + dxx;
            vb = ((unsigned)yy < (unsigned)HH) && ((unsigned)xx < (unsigned)WW);
            a1 = *(const uint4*)(xb + (size_t)(vb ? (pB + off) : 0)*64 + sc*8);
        }
        if (BROWS == 32 || bn < BROWS)
            bb = *(const uint4*)(wbase + ((size_t)tap*NP + bn)*64 + sc*8);
    };

    uint4 rA0[TPB], rA1[TPB], rB[TPB];
    bool v0[TPB], v1[TPB];
    #pragma unroll
    for (int tt = 0; tt < TPB; ++tt) {
        rA0[tt] = z4; rA1[tt] = z4; rB[tt] = z4; v0[tt] = false; v1[tt] = false;
        if (tt < KK) LD(tt, rA0[tt], rA1[tt], v0[tt], v1[tt], rB[tt]);
    }

    #pragma unroll
    for (int p = 0; p < NPH; ++p) {
        uint4 nA0[TPB], nA1[TPB], nB[TPB];
        bool nv0[TPB], nv1[TPB];
        #pragma unroll
        for (int tt = 0; tt < TPB; ++tt) {
            nA0[tt] = z4; nA1[tt] = z4; nB[tt] = z4; nv0[tt] = false; nv1[tt] = false;
            const int tap = (p + 1)*TPB + tt;
            if (tap < KK) LD(tap, nA0[tt], nA1[tt], nv0[tt], nv1[tt], nB[tt]);
        }

        u16* A  = &Ab[p & 1][0];
        u16* Bq = &Bb[p & 1][0];
        #pragma unroll
        for (int tt = 0; tt < TPB; ++tt) {
            if (p*TPB + tt < KK) {
                *(uint4*)(A + tt*4096 + spx*64      + sslotA) = selz(v0[tt], rA0[tt]);
                *(uint4*)(A + tt*4096 + (spx+32)*64 + sslotA) = selz(v1[tt], rA1[tt]);
                if (BROWS == 32 || bn < BROWS)
                    *(uint4*)(Bq + tt*BROWS*64 + bn*64 + bslot) = rB[tt];
            }
        }
        __syncthreads();

        #pragma unroll
        for (int tt = 0; tt < TPB; ++tt) {
            if (p*TPB + tt < KK) {
                const bf16x8 av0 = *(const bf16x8*)(A + tt*4096 + arow + a0s);
                const bf16x8 av1 = *(const bf16x8*)(A + tt*4096 + arow + a1s);
                #pragma unroll
                for (int h = 0; h < NTW; ++h) {
                    const int brow = tt*BROWS*64 + (h*16 + r)*64;
                    const bf16x8 bv0 = *(const bf16x8*)(Bq + brow + b0s);
                    const bf16x8 bv1 = *(const bf16x8*)(Bq + brow + b1s);
                    acc[h] = __builtin_amdgcn_mfma_f32_16x16x32_bf16(av0, bv0, acc[h], 0, 0, 0);
                    acc[h] = __builtin_amdgcn_mfma_f32_16x16x32_bf16(av1, bv1, acc[h], 0, 0, 0);
                }
            }
        }

        #pragma unroll
        for (int tt = 0; tt < TPB; ++tt) {
            rA0[tt] = nA0[tt]; rA1[tt] = nA1[tt]; rB[tt] = nB[tt];
            v0[tt] = nv0[tt]; v1[tt] = nv1[tt];
        }
    }

    #pragma unroll
    for (int h = 0; h < NTW; ++h) {
        const int n = nt0*BROWS + h*16 + r;
        if (n < COUT) {
            const float bv = bias[n];
            float* op = out + ((size_t)b*HW + p0 + wave*16 + quad*4)*NPAD + n;
            #pragma unroll
            for (int r2 = 0; r2 < 4; ++r2) op[(size_t)r2*NPAD] = acc[h][r2] + bv;
        }
    }
}

// ---------------------------------------------------------------------------
// Two-phase deform, 2 channels/lane, R5 software-pipelined tap loop
// (measured-best; 8 px/block, grid 1568, 24 waves/CU, single barrier).
// ---------------------------------------------------------------------------
template<int K, int DIL, int PAD, int NPAD>
__global__ __launch_bounds__(256)
void deform_cl_kernel(const u16* __restrict__ inT, const float* __restrict__ offT,
                      const float* __restrict__ dwT, u16* __restrict__ outT) {
    constexpr int KK = K*K;
    __shared__ float4 swt[8][KK];
    __shared__ int4   sat[8][KK];
    __shared__ float  sdw[KK*64];

    const int t = threadIdx.x;
    const int nb8 = (BB*HW/8) >> 3;               // 196
    const int blk0 = blockIdx.x;
    const int blk = (blk0 & 7)*nb8 + (blk0 >> 3); // XCD-contiguous pixels
    const int p0 = blk*8;
    const int b  = p0 / HW;                       // 8 | HW -> same batch
    const int pl0 = p0 - b*HW;

    for (int i = t; i < KK*64; i += 256) sdw[i] = dwT[i];

    for (int i = t; i < 8*KK; i += 256) {
        const int pix = i / KK, k = i - pix*KK;
        const int pl  = pl0 + pix;
        const int h = pl / WW, w = pl % WW;
        const float* orow = offT + ((size_t)b*HW + pl)*NPAD;
        const float dy = orow[2*k];
        const float dx = orow[2*k+1];
        const float py = (float)(h + (k/K)*DIL - PAD) + dy;
        const float px = (float)(w + (k%K)*DIL - PAD) + dx;
        const float y0f = floorf(py), x0f = floorf(px);
        const float wy1 = py - y0f,  wx1 = px - x0f;
        const float wy0 = 1.f - wy1, wx0 = 1.f - wx1;
        const int y0 = (int)y0f, x0 = (int)x0f;

        const int y0c = min(max(y0,   0), HH-1);
        const int y1c = min(max(y0+1, 0), HH-1);
        const int x0c = min(max(x0,   0), WW-1);
        const int x1c = min(max(x0+1, 0), WW-1);
        const float gy0 = wy0 * ((y0   >= 0 && y0   < HH) ? 1.f : 0.f);
        const float gy1 = wy1 * ((y0+1 >= 0 && y0+1 < HH) ? 1.f : 0.f);
        const float gx0 = wx0 * ((x0   >= 0 && x0   < WW) ? 1.f : 0.f);
        const float gx1 = wx1 * ((x0+1 >= 0 && x0+1 < WW) ? 1.f : 0.f);

        swt[pix][k] = make_float4(gy0*gx0, gy0*gx1, gy1*gx0, gy1*gx1);
        const int r0 = y0c*WW, r1 = y1c*WW;
        sat[pix][k] = make_int4((r0 + x0c) << 7, (r0 + x1c) << 7,
                                (r1 + x0c) << 7, (r1 + x1c) << 7);
    }
    __syncthreads();

    const int wave = t >> 6, lane = t & 63;
    const int pixl = 2*wave + (lane >> 5);        // 0..7 (half-wave = pixel)
    const int chp  = lane & 31;                   // channel pair 0..31
    const char* ib = (const char*)(inT + (size_t)b*HW*64) + chp*4;

    float accx = 0.f, accy = 0.f;

    int4   av[3];
    float4 wv[2];
    float2 dv[2];
    u32 c00[2], c01[2], c10[2], c11[2];

    av[0] = sat[pixl][0];
    if (KK > 1) av[1] = sat[pixl][1];
    wv[0] = swt[pixl][0];
    dv[0] = *(const float2*)&sdw[2*chp];
    c00[0] = *(const u32*)(ib + av[0].x);
    c01[0] = *(const u32*)(ib + av[0].y);
    c10[0] = *(const u32*)(ib + av[0].z);
    c11[0] = *(const u32*)(ib + av[0].w);

    #pragma unroll
    for (int k = 0; k < KK; ++k) {
        const int kn = k + 1;
        if (kn + 1 < KK) av[(kn+1)%3] = sat[pixl][kn+1];
        if (kn < KK) {
            wv[kn&1] = swt[pixl][kn];
            dv[kn&1] = *(const float2*)&sdw[kn*64 + 2*chp];
            const int4 a = av[kn%3];
            c00[kn&1] = *(const u32*)(ib + a.x);
            c01[kn&1] = *(const u32*)(ib + a.y);
            c10[kn&1] = *(const u32*)(ib + a.z);
            c11[kn&1] = *(const u32*)(ib + a.w);
        }
        const float4 w = wv[k&1];
        const u32 u00 = c00[k&1], u01 = c01[k&1], u10 = c10[k&1], u11 = c11[k&1];
        const float sx = lo_f(u00)*w.x + lo_f(u01)*w.y + lo_f(u10)*w.z + lo_f(u11)*w.w;
        const float sy = hi_f(u00)*w.x + hi_f(u01)*w.y + hi_f(u10)*w.z + hi_f(u11)*w.w;
        const float2 d = dv[k&1];
        accx += sx * d.x;
        accy += sy * d.y;
    }

    const u32 o = (u32)f2bf(accx) | ((u32)f2bf(accy) << 16);
    *(u32*)((char*)outT + (size_t)(p0 + pixl)*128 + chp*4) = o;
}

// ---------------------------------------------------------------------------
// Pointwise 1x1 via MFMA + fused residual multiply; wave = 16 px x 1 n-tile.
// ---------------------------------------------------------------------------
__global__ __launch_bounds__(256)
void pw_mfma_kernel(const u16* __restrict__ a2T, const u16* __restrict__ pwT,
                    const float* __restrict__ pb, const float* __restrict__ x,
                    float* __restrict__ out) {
    const int nm = HW/64;
    const int b  = blockIdx.x / nm;
    const int p0 = (blockIdx.x % nm)*64 + (threadIdx.x >> 6)*16;
    const int nt = blockIdx.y;
    const int lane = threadIdx.x & 63;
    const int r = lane & 15, quad = lane >> 4;

    const u16* ap = a2T + ((size_t)b*HW + p0 + r)*64 + quad*8;
    f32x4 acc = (f32x4){0.f,0.f,0.f,0.f};
    #pragma unroll
    for (int ks = 0; ks < 2; ++ks) {
        const bf16x8 av = *(const bf16x8*)(ap + ks*32);
        const bf16x8 bv = *(const bf16x8*)(pwT + ((size_t)(nt*16 + r))*64 + ks*32 + quad*8);
        acc = __builtin_amdgcn_mfma_f32_16x16x32_bf16(av, bv, acc, 0, 0, 0);
    }

    const int n = nt*16 + r;
    const float bv = pb[n];
    const size_t base = ((size_t)b*CC + n)*HW + p0 + quad*4;
    #pragma unroll
    for (int r2 = 0; r2 < 4; ++r2)
        out[base + r2] = x[base + r2] * (acc[r2] + bv);
}

// ======================= fallback fp32 kernels (low ws) =====================
template<int K, int DIL, int PAD, int COUT, int OCB>
__global__ __launch_bounds__(256)
void off_conv_sg_kernel(const float* __restrict__ in, const float* __restrict__ wgt,
                        const float* __restrict__ bias, float* __restrict__ out) {
    constexpr int KK = K*K;
    const int nOB = COUT / OCB;
    const int b   = blockIdx.x / nOB;
    const int oc0 = (blockIdx.x % nOB) * OCB;
    const int x   = threadIdx.x;
    const int h   = blockIdx.y*4 + threadIdx.y;

    float acc[OCB];
    #pragma unroll
    for (int o = 0; o < OCB; ++o) acc[o] = bias[oc0+o];

    const float* inb = in + (size_t)b*CC*HW;
    const float* wb  = wgt + (size_t)oc0*CC*KK;

    for (int ic = 0; ic < CC; ++ic) {
        const float* inp = inb + ic*HW;
        const float* wp  = wb + ic*KK;
        #pragma unroll
        for (int ky = 0; ky < K; ++ky) {
            const int  y  = h + ky*DIL - PAD;
            const bool yv = (y >= 0) && (y < HH);
            const int  yc = yv ? y : 0;
            const float* row = inp + yc*WW;
            #pragma unroll
            for (int kx = 0; kx < K; ++kx) {
                const int  xx = x + kx*DIL - PAD;
                const bool v  = yv && (xx >= 0) && (xx < WW);
                const int  xc = (xx < 0) ? 0 : ((xx >= WW) ? (WW-1) : xx);
                float val = row[xc];
                val = v ? val : 0.f;
                const int t = ky*K + kx;
                #pragma unroll
                for (int o = 0; o < OCB; ++o)
                    acc[o] += wp[(size_t)o*CC*KK + t] * val;
            }
        }
    }

    if (x >= WW) return;
    #pragma unroll
    for (int o = 0; o < OCB; ++o)
        out[((size_t)b*COUT + oc0 + o)*HW + h*WW + x] = acc[o];
}

template<int K, int DIL, int PAD>
__global__ __launch_bounds__(64)
void deform_dw_full_kernel(const float* __restrict__ in, const float* __restrict__ off,
                           const float* __restrict__ dw, float* __restrict__ out) {
    constexpr int KK = K*K;
    const int idx = blockIdx.x*64 + threadIdx.x;
    const int x = idx % WW;
    const int h = (idx / WW) % HH;
    const int c = (idx / HW) % CC;
    const int b = idx / (CC*HW);

    const float* inp  = in  + ((size_t)b*CC + c)*HW;
    const float* offp = off + (size_t)b*(2*KK)*HW + h*WW + x;
    const float* dwp  = dw  + c*KK;

    float acc = 0.f;
    #pragma unroll 7
    for (int k = 0; k < KK; ++k) {
        const float dy = offp[(2*k  )*HW];
        const float dx = offp[(2*k+1)*HW];
        const float py = (float)(h + (k/K)*DIL - PAD) + dy;
        const float px = (float)(x + (k%K)*DIL - PAD) + dx;
        const float y0f = floorf(py), x0f = floorf(px);
        const float wy1 = py - y0f,  wx1 = px - x0f;
        const float wy0 = 1.f - wy1, wx0 = 1.f - wx1;
        const int y0 = (int)y0f, x0 = (int)x0f;

        const int y0c = min(max(y0,   0), HH-1);
        const int y1c = min(max(y0+1, 0), HH-1);
        const int x0c = min(max(x0,   0), WW-1);
        const int x1c = min(max(x0+1, 0), WW-1);
        const float my0 = (y0   >= 0 && y0   < HH) ? 1.f : 0.f;
        const float my1 = (y0+1 >= 0 && y0+1 < HH) ? 1.f : 0.f;
        const float mx0 = (x0   >= 0 && x0   < WW) ? 1.f : 0.f;
        const float mx1 = (x0+1 >= 0 && x0+1 < WW) ? 1.f : 0.f;

        const float v00 = inp[y0c*WW + x0c];
        const float v01 = inp[y0c*WW + x1c];
        const float v10 = inp[y1c*WW + x0c];
        const float v11 = inp[y1c*WW + x1c];

        const float gx0 = wx0*mx0, gx1 = wx1*mx1;
        const float s = (v00*gx0 + v01*gx1) * (wy0*my0)
                      + (v10*gx0 + v11*gx1) * (wy1*my1);
        acc += s * dwp[k];
    }
    out[idx] = acc;
}

__global__ __launch_bounds__(256)
void pw_mul_kernel(const float* __restrict__ x, const float* __restrict__ a2,
                   const float* __restrict__ pw, const float* __restrict__ pb,
                   float* __restrict__ out) {
    constexpr int HW4 = HW/4;
    const int t = blockIdx.x*256 + threadIdx.x;
    if (t >= BB*CC*HW4) return;
    const int sp4 = t % HW4;
    const int oc  = (t / HW4) % CC;
    const int b   = t / (CC*HW4);

    const float4* ap = (const float4*)(a2 + (size_t)b*CC*HW) + sp4;
    const float4* wp4 = (const float4*)(pw + oc*CC);
    const float pbv = pb[oc];
    float4 acc = make_float4(pbv, pbv, pbv, pbv);
    #pragma unroll 4
    for (int ic4 = 0; ic4 < CC/4; ++ic4) {
        const float4 w = wp4[ic4];
        float4 a0 = ap[(ic4*4+0)*HW4];
        float4 a1 = ap[(ic4*4+1)*HW4];
        float4 a2v = ap[(ic4*4+2)*HW4];
        float4 a3 = ap[(ic4*4+3)*HW4];
        acc.x += w.x*a0.x + w.y*a1.x + w.z*a2v.x + w.w*a3.x;
        acc.y += w.x*a0.y + w.y*a1.y + w.z*a2v.y + w.w*a3.y;
        acc.z += w.x*a0.z + w.y*a1.z + w.z*a2v.z + w.w*a3.z;
        acc.w += w.x*a0.w + w.y*a1.w + w.z*a2v.w + w.w*a3.w;
    }
    const float4 xv = ((const float4*)x)[t];
    float4 r;
    r.x = xv.x*acc.x; r.y = xv.y*acc.y; r.z = xv.z*acc.z; r.w = xv.w*acc.w;
    ((float4*)out)[t] = r;
}

extern "C" void kernel_launch(void* const* d_in, const int* in_sizes, int n_in,
                              void* d_out, int out_size, void* d_ws, size_t ws_size,
                              hipStream_t stream) {
    const float* x      = (const float*)d_in[0];
    const float* off_w1 = (const float*)d_in[1];
    const float* off_b1 = (const float*)d_in[2];
    const float* dw_w1  = (const float*)d_in[3];
    const float* off_w2 = (const float*)d_in[4];
    const float* off_b2 = (const float*)d_in[5];
    const float* dw_w2  = (const float*)d_in[6];
    const float* pw_w   = (const float*)d_in[7];
    const float* pw_b   = (const float*)d_in[8];
    float* out = (float*)d_out;

    const size_t nF    = (size_t)BB*CC*HW;
    const size_t attnB = nF*sizeof(float);
    const size_t off2B = (size_t)BB*98*HW*sizeof(float);   // fallback layout
    const size_t offTB = (size_t)BB*HW*112*sizeof(float);  // transposed offsets
    const size_t chB   = (size_t)BB*HW*64*sizeof(u16);
    char* ws = (char*)d_ws;

    const int n    = (int)nF;
    const int dbl  = n/64;
    const int pbl  = (n/4 + 255)/256;
    dim3 cblk(64,4);
    dim3 rgrd1(BB*(50/5), HH/4);
    dim3 rgrd2(BB*(98/7), HH/4);
    dim3 cgrd1(TGRID, 4);                    // conv1: 4 x 16-n tiles (NTW=1)
    dim3 cgrd2(TGRID, 4);                    // conv2: 4 x 32-n tiles (NTW=2)
    dim3 pgrd(TGRID, 4);                     // pw
    const int dgrid = BB*HW/8;               // 1568 (8 pixels per block)

    const size_t oOFF  = 0;
    const size_t oXT   = oOFF + offTB;
    const size_t oA1T  = oXT  + chB;
    const size_t oA2T  = oA1T + chB;
    const size_t oW1   = oA2T + chB;
    const size_t oW2   = oW1  + (size_t)R1*2;
    const size_t oPWT  = oW2  + (size_t)R2*2;
    const size_t oDW1  = oPWT + (size_t)R3*2;
    const size_t oDW2  = oDW1 + (size_t)R4*4;
    const size_t TOT   = oDW2 + (size_t)R5*4;   // ~11.47 MB

    if (ws_size >= TOT) {
        float* off_buf = (float*)(ws + oOFF);
        u16*   xT      = (u16*)(ws + oXT);
        u16*   a1T     = (u16*)(ws + oA1T);
        u16*   a2T     = (u16*)(ws + oA2T);
        u16*   w2t1    = (u16*)(ws + oW1);
        u16*   w2t2    = (u16*)(ws + oW2);
        u16*   pwT     = (u16*)(ws + oPWT);
        float* dwT1    = (float*)(ws + oDW1);
        float* dwT2    = (float*)(ws + oDW2);

        prep_tr_kernel<<<TGRID + (PREPN+255)/256, 256, 0, stream>>>(
            x, off_w1, off_w2, pw_w, dw_w1, dw_w2,
            xT, w2t1, w2t2, pwT, dwT1, dwT2);

        conv_mfma_lds_kernel<5,1,2,50,64,64,1><<<cgrd1, 256, 0, stream>>>(xT, w2t1, off_b1, off_buf);
        deform_cl_kernel<5,1,2,64><<<dgrid, 256, 0, stream>>>(xT, off_buf, dwT1, a1T);

        conv_mfma_lds_kernel<7,3,9,98,128,112,2><<<cgrd2, 256, 0, stream>>>(a1T, w2t2, off_b2, off_buf);
        deform_cl_kernel<7,3,9,112><<<dgrid, 256, 0, stream>>>(a1T, off_buf, dwT2, a2T);

        pw_mfma_kernel<<<pgrd, 256, 0, stream>>>(a2T, pwT, pw_b, x, out);
    } else if (ws_size >= off2B + attnB) {
        float* off_buf = (float*)ws;
        float* attn1   = (float*)d_out;
        float* attn2   = (float*)(ws + off2B);
        off_conv_sg_kernel<5,1,2,50,5><<<rgrd1, cblk, 0, stream>>>(x, off_w1, off_b1, off_buf);
        deform_dw_full_kernel<5,1,2><<<dbl, 64, 0, stream>>>(x, off_buf, dw_w1, attn1);
        off_conv_sg_kernel<7,3,9,98,7><<<rgrd2, cblk, 0, stream>>>(attn1, off_w2, off_b2, off_buf);
        deform_dw_full_kernel<7,3,9><<<dbl, 64, 0, stream>>>(attn1, off_buf, dw_w2, attn2);
        pw_mul_kernel<<<pbl, 256, 0, stream>>>(x, attn2, pw_w, pw_b, out);
    } else {
        float* attn1 = (float*)d_out;
        float* attn2 = (float*)ws;
        float* off1  = (float*)ws;
        off_conv_sg_kernel<5,1,2,50,5><<<rgrd1, cblk, 0, stream>>>(x, off_w1, off_b1, off1);
        deform_dw_full_kernel<5,1,2><<<dbl, 64, 0, stream>>>(x, off1, dw_w1, attn1);
        float* off2 = (float*)(ws + attnB);
        off_conv_sg_kernel<7,3,9,98,7><<<rgrd2, cblk, 0, stream>>>(attn1, off_w2, off_b2, off2);
        deform_dw_full_kernel<7,3,9><<<dbl, 64, 0, stream>>>(attn1, off2, dw_w2, attn2);
        pw_mul_kernel<<<pbl, 256, 0, stream>>>(x, attn2, pw_w, pw_b, out);
    }
}

// Round 10
// 155.449 us; speedup vs baseline: 1.3765x; 1.0350x over previous
//
#include <hip/hip_runtime.h>

// Problem constants (from reference setup_inputs)
#define BB 4
#define CC 64
#define HH 56
#define WW 56
#define HW (HH*WW)

typedef unsigned short u16;
typedef unsigned int u32;
typedef __attribute__((ext_vector_type(8))) short bf16x8;
typedef __attribute__((ext_vector_type(4))) float f32x4;

__device__ __forceinline__ u16 f2bf(float f) {
    union { float f; unsigned u; } c; c.f = f;
    unsigned u = c.u;
    u = (u + 0x7FFFu + ((u >> 16) & 1u)) >> 16;   // RNE
    return (u16)u;
}
__device__ __forceinline__ float lo_f(u32 u) {   // bf16 pair -> lo fp32
    union { unsigned u; float f; } c; c.u = u << 16; return c.f;
}
__device__ __forceinline__ float hi_f(u32 u) {   // bf16 pair -> hi fp32
    union { unsigned u; float f; } c; c.u = u & 0xffff0000u; return c.f;
}

// ---------------------------------------------------------------------------
// Fused prep + input transpose in ONE launch (R5 baseline).
// ---------------------------------------------------------------------------
#define R1 102400
#define R2 401408
#define R3 4096
#define R4 1600
#define R5 3136
#define TGRID (BB*(HW/64))          // 196
#define PREPN (R1+R2+R3+R4+R5)
__global__ __launch_bounds__(256)
void prep_tr_kernel(const float* __restrict__ x,
                    const float* __restrict__ ow1, const float* __restrict__ ow2,
                    const float* __restrict__ pw,  const float* __restrict__ dw1,
                    const float* __restrict__ dw2,
                    u16* __restrict__ xT,
                    u16* __restrict__ w2t1, u16* __restrict__ w2t2,
                    u16* __restrict__ pwT, float* __restrict__ dwT1,
                    float* __restrict__ dwT2) {
    __shared__ u16 tile[64][72];
    const int t = threadIdx.x;
    if (blockIdx.x < TGRID) {
        const int blk = blockIdx.x;
        const int b   = blk / (HW/64);
        const int p0  = (blk % (HW/64))*64;
        const int px  = t & 63, icq = t >> 6;
        const float* ip = x + ((size_t)b*CC + icq*16)*HW + p0 + px;
        #pragma unroll
        for (int i = 0; i < 16; ++i)
            tile[px][icq*16 + i] = f2bf(ip[(size_t)i*HW]);
        __syncthreads();
        const int px2 = t >> 2, g = t & 3;
        u16* op = xT + ((size_t)b*HW + p0 + px2)*64 + g*16;
        const uint4* s = (const uint4*)&tile[px2][g*16];
        ((uint4*)op)[0] = s[0];
        ((uint4*)op)[1] = s[1];
        return;
    }
    const int i = (blockIdx.x - TGRID)*256 + t;
    if (i < R1) {
        const int ic = i & 63, n = (i >> 6) & 63, tap = i >> 12;
        w2t1[i] = f2bf((n < 50) ? ow1[((size_t)n*64 + ic)*25 + tap] : 0.f);
    } else if (i < R1+R2) {
        const int j = i - R1;
        const int ic = j & 63, n = (j >> 6) & 127, tap = j >> 13;
        w2t2[j] = f2bf((n < 98) ? ow2[((size_t)n*64 + ic)*49 + tap] : 0.f);
    } else if (i < R1+R2+R3) {
        const int j = i - (R1+R2);
        pwT[j] = f2bf(pw[j]);
    } else if (i < R1+R2+R3+R4) {
        const int j = i - (R1+R2+R3);
        const int c = j & 63, k = j >> 6;
        dwT1[j] = dw1[c*25 + k];
    } else if (i < R1+R2+R3+R4+R5) {
        const int j = i - (R1+R2+R3+R4);
        const int c = j & 63, k = j >> 6;
        dwT2[j] = dw2[c*49 + k];
    }
}

__device__ __forceinline__ uint4 selz(bool v, uint4 a) {
    const uint4 z = make_uint4(0,0,0,0);
    return v ? a : z;
}

// ---------------------------------------------------------------------------
// LDS-staged MFMA implicit-GEMM conv (exact R5 form, measured-best total).
// NTW=2, transposed output (B,HW,NPAD) fp32.
// ---------------------------------------------------------------------------
template<int K, int DIL, int PAD, int COUT, int NP, int NPAD, int NTW>
__global__ __launch_bounds__(256, 4)
void conv_mfma_lds_kernel(const u16* __restrict__ xT, const u16* __restrict__ w2t,
                          const float* __restrict__ bias, float* __restrict__ out) {
    constexpr int KK = K*K;
    constexpr int BROWS = 16*NTW;
    __shared__ u16 Ab[2][64*64];
    __shared__ u16 Bb[2][BROWS*64];

    const int nm   = HW/64;                       // 49
    const int b    = blockIdx.x / nm;
    const int p0   = (blockIdx.x % nm)*64;
    const int nt0  = blockIdx.y;
    const int t    = threadIdx.x;
    const int wave = t >> 6;
    const int lane = t & 63;

    const int spx = t >> 3;                       // 0..31
    const int sc  = t & 7;                        // chunk 0..7
    const int pA  = p0 + spx;
    const int pB  = p0 + spx + 32;
    const int pyA = pA / WW, pxA = pA % WW;
    const int pyB = pB / WW, pxB = pB % WW;
    const u16* xb = xT + (size_t)b*HW*64;
    const int sslotA = ((sc + spx) & 7)*8;
    const int bn  = t >> 3;                       // 0..31
    const int bslot = ((sc + bn) & 7)*8;
    const u16* wbase = w2t + (size_t)nt0*BROWS*64;

    const int r = lane & 15, quad = lane >> 4;
    const int mloc = wave*16 + r;
    const int arow = mloc*64;
    const int a0s = ((quad     + mloc) & 7)*8;
    const int a1s = ((quad + 4 + mloc) & 7)*8;
    const int b0s = ((quad     + r) & 7)*8;
    const int b1s = ((quad + 4 + r) & 7)*8;

    f32x4 acc[NTW];
    #pragma unroll
    for (int h = 0; h < NTW; ++h) acc[h] = (f32x4){0.f,0.f,0.f,0.f};
    const uint4 z4 = make_uint4(0,0,0,0);

    auto LD = [&](int tap, uint4& a0, uint4& a1, bool& va, bool& vb, uint4& bb) {
        const int dyy = (tap/K)*DIL - PAD;
        const int dxx = (tap%K)*DIL - PAD;
        const int off = dyy*WW + dxx;
        {
            const int yy = pyA + dyy, xx = pxA + dxx;
            va = ((unsigned)yy < (unsigned)HH) && ((unsigned)xx < (unsigned)WW);
            a0 = *(const uint4*)(xb + (size_t)(va ? (pA + off) : 0)*64 + sc*8);
        }
        {
            const int yy = pyB + dyy, xx = pxB + dxx;
            vb = ((unsigned)yy < (unsigned)HH) && ((unsigned)xx < (unsigned)WW);
            a1 = *(const uint4*)(xb + (size_t)(vb ? (pB + off) : 0)*64 + sc*8);
        }
        if (BROWS == 32 || bn < BROWS)
            bb = *(const uint4*)(wbase + ((size_t)tap*NP + bn)*64 + sc*8);
    };

    uint4 rA0 = z4, rA1 = z4, rB = z4;
    bool v0 = false, v1 = false;
    LD(0, rA0, rA1, v0, v1, rB);

    #pragma unroll
    for (int tap = 0; tap < KK; ++tap) {
        uint4 nA0 = z4, nA1 = z4, nB = z4;
        bool nv0 = false, nv1 = false;
        if (tap + 1 < KK) LD(tap + 1, nA0, nA1, nv0, nv1, nB);

        u16* A  = &Ab[tap & 1][0];
        u16* Bq = &Bb[tap & 1][0];
        *(uint4*)(A + spx*64      + sslotA) = selz(v0, rA0);
        *(uint4*)(A + (spx+32)*64 + sslotA) = selz(v1, rA1);
        if (BROWS == 32 || bn < BROWS) *(uint4*)(Bq + bn*64 + bslot) = rB;
        __syncthreads();

        const bf16x8 av0 = *(const bf16x8*)(A + arow + a0s);
        const bf16x8 av1 = *(const bf16x8*)(A + arow + a1s);
        #pragma unroll
        for (int h = 0; h < NTW; ++h) {
            const int brow = (h*16 + r)*64;
            const bf16x8 bv0 = *(const bf16x8*)(Bq + brow + b0s);
            const bf16x8 bv1 = *(const bf16x8*)(Bq + brow + b1s);
            acc[h] = __builtin_amdgcn_mfma_f32_16x16x32_bf16(av0, bv0, acc[h], 0, 0, 0);
            acc[h] = __builtin_amdgcn_mfma_f32_16x16x32_bf16(av1, bv1, acc[h], 0, 0, 0);
        }

        rA0 = nA0; rA1 = nA1; rB = nB; v0 = nv0; v1 = nv1;
    }

    #pragma unroll
    for (int h = 0; h < NTW; ++h) {
        const int n = nt0*BROWS + h*16 + r;
        if (n < COUT) {
            const float bv = bias[n];
            float* op = out + ((size_t)b*HW + p0 + wave*16 + quad*4)*NPAD + n;
            #pragma unroll
            for (int r2 = 0; r2 < 4; ++r2) op[(size_t)r2*NPAD] = acc[h][r2] + bv;
        }
    }
}

// ---------------------------------------------------------------------------
// Two-phase deform, 2 channels/lane, DEEPENED software pipeline:
// corner loads prefetched 2 taps ahead (ring-of-3), addresses 3 ahead
// (ring-of-4), wv/dv 1 ahead (unchanged). Doubles outstanding VMEM per
// wave (4 -> 8) to close the Little's-law gap vs ~200cy L2 latency.
// Baseline layout kept: 8 px/block, grid 1568, ~24 waves/CU, one barrier.
// FMA order identical to baseline -> bit-identical result.
// ---------------------------------------------------------------------------
template<int K, int DIL, int PAD, int NPAD>
__global__ __launch_bounds__(256)
void deform_cl_kernel(const u16* __restrict__ inT, const float* __restrict__ offT,
                      const float* __restrict__ dwT, u16* __restrict__ outT) {
    constexpr int KK = K*K;
    __shared__ float4 swt[8][KK];
    __shared__ int4   sat[8][KK];
    __shared__ float  sdw[KK*64];

    const int t = threadIdx.x;
    const int nb8 = (BB*HW/8) >> 3;               // 196
    const int blk0 = blockIdx.x;
    const int blk = (blk0 & 7)*nb8 + (blk0 >> 3); // XCD-contiguous pixels
    const int p0 = blk*8;
    const int b  = p0 / HW;                       // 8 | HW -> same batch
    const int pl0 = p0 - b*HW;

    for (int i = t; i < KK*64; i += 256) sdw[i] = dwT[i];

    for (int i = t; i < 8*KK; i += 256) {
        const int pix = i / KK, k = i - pix*KK;
        const int pl  = pl0 + pix;
        const int h = pl / WW, w = pl % WW;
        const float* orow = offT + ((size_t)b*HW + pl)*NPAD;
        const float dy = orow[2*k];
        const float dx = orow[2*k+1];
        const float py = (float)(h + (k/K)*DIL - PAD) + dy;
        const float px = (float)(w + (k%K)*DIL - PAD) + dx;
        const float y0f = floorf(py), x0f = floorf(px);
        const float wy1 = py - y0f,  wx1 = px - x0f;
        const float wy0 = 1.f - wy1, wx0 = 1.f - wx1;
        const int y0 = (int)y0f, x0 = (int)x0f;

        const int y0c = min(max(y0,   0), HH-1);
        const int y1c = min(max(y0+1, 0), HH-1);
        const int x0c = min(max(x0,   0), WW-1);
        const int x1c = min(max(x0+1, 0), WW-1);
        const float gy0 = wy0 * ((y0   >= 0 && y0   < HH) ? 1.f : 0.f);
        const float gy1 = wy1 * ((y0+1 >= 0 && y0+1 < HH) ? 1.f : 0.f);
        const float gx0 = wx0 * ((x0   >= 0 && x0   < WW) ? 1.f : 0.f);
        const float gx1 = wx1 * ((x0+1 >= 0 && x0+1 < WW) ? 1.f : 0.f);

        swt[pix][k] = make_float4(gy0*gx0, gy0*gx1, gy1*gx0, gy1*gx1);
        const int r0 = y0c*WW, r1 = y1c*WW;
        sat[pix][k] = make_int4((r0 + x0c) << 7, (r0 + x1c) << 7,
                                (r1 + x0c) << 7, (r1 + x1c) << 7);
    }
    __syncthreads();

    const int wave = t >> 6, lane = t & 63;
    const int pixl = 2*wave + (lane >> 5);        // 0..7 (half-wave = pixel)
    const int chp  = lane & 31;                   // channel pair 0..31
    const char* ib = (const char*)(inT + (size_t)b*HW*64) + chp*4;

    float accx = 0.f, accy = 0.f;

    int4   av[4];
    float4 wv[2];
    float2 dv[2];
    u32 c00[3], c01[3], c10[3], c11[3];

    // prologue: addresses taps 0..2; corners taps 0,1; weights tap 0
    av[0] = sat[pixl][0];
    if (KK > 1) av[1] = sat[pixl][1];
    if (KK > 2) av[2] = sat[pixl][2];
    wv[0] = swt[pixl][0];
    dv[0] = *(const float2*)&sdw[2*chp];
    c00[0] = *(const u32*)(ib + av[0].x);
    c01[0] = *(const u32*)(ib + av[0].y);
    c10[0] = *(const u32*)(ib + av[0].z);
    c11[0] = *(const u32*)(ib + av[0].w);
    if (KK > 1) {
        c00[1] = *(const u32*)(ib + av[1].x);
        c01[1] = *(const u32*)(ib + av[1].y);
        c10[1] = *(const u32*)(ib + av[1].z);
        c11[1] = *(const u32*)(ib + av[1].w);
    }

    #pragma unroll
    for (int k = 0; k < KK; ++k) {
        if (k + 3 < KK) av[(k+3)&3] = sat[pixl][k+3];     // addr 3 ahead
        if (k + 2 < KK) {                                  // corners 2 ahead
            const int4 a = av[(k+2)&3];
            c00[(k+2)%3] = *(const u32*)(ib + a.x);
            c01[(k+2)%3] = *(const u32*)(ib + a.y);
            c10[(k+2)%3] = *(const u32*)(ib + a.z);
            c11[(k+2)%3] = *(const u32*)(ib + a.w);
        }
        if (k + 1 < KK) {                                  // weights 1 ahead
            wv[(k+1)&1] = swt[pixl][k+1];
            dv[(k+1)&1] = *(const float2*)&sdw[(k+1)*64 + 2*chp];
        }
        const float4 w = wv[k&1];
        const u32 u00 = c00[k%3], u01 = c01[k%3], u10 = c10[k%3], u11 = c11[k%3];
        const float sx = lo_f(u00)*w.x + lo_f(u01)*w.y + lo_f(u10)*w.z + lo_f(u11)*w.w;
        const float sy = hi_f(u00)*w.x + hi_f(u01)*w.y + hi_f(u10)*w.z + hi_f(u11)*w.w;
        const float2 d = dv[k&1];
        accx += sx * d.x;
        accy += sy * d.y;
    }

    const u32 o = (u32)f2bf(accx) | ((u32)f2bf(accy) << 16);
    *(u32*)((char*)outT + (size_t)(p0 + pixl)*128 + chp*4) = o;
}

// ---------------------------------------------------------------------------
// Pointwise 1x1 via MFMA + fused residual multiply; wave = 16 px x 1 n-tile.
// ---------------------------------------------------------------------------
__global__ __launch_bounds__(256)
void pw_mfma_kernel(const u16* __restrict__ a2T, const u16* __restrict__ pwT,
                    const float* __restrict__ pb, const float* __restrict__ x,
                    float* __restrict__ out) {
    const int nm = HW/64;
    const int b  = blockIdx.x / nm;
    const int p0 = (blockIdx.x % nm)*64 + (threadIdx.x >> 6)*16;
    const int nt = blockIdx.y;
    const int lane = threadIdx.x & 63;
    const int r = lane & 15, quad = lane >> 4;

    const u16* ap = a2T + ((size_t)b*HW + p0 + r)*64 + quad*8;
    f32x4 acc = (f32x4){0.f,0.f,0.f,0.f};
    #pragma unroll
    for (int ks = 0; ks < 2; ++ks) {
        const bf16x8 av = *(const bf16x8*)(ap + ks*32);
        const bf16x8 bv = *(const bf16x8*)(pwT + ((size_t)(nt*16 + r))*64 + ks*32 + quad*8);
        acc = __builtin_amdgcn_mfma_f32_16x16x32_bf16(av, bv, acc, 0, 0, 0);
    }

    const int n = nt*16 + r;
    const float bv = pb[n];
    const size_t base = ((size_t)b*CC + n)*HW + p0 + quad*4;
    #pragma unroll
    for (int r2 = 0; r2 < 4; ++r2)
        out[base + r2] = x[base + r2] * (acc[r2] + bv);
}

// ======================= fallback fp32 kernels (low ws) =====================
template<int K, int DIL, int PAD, int COUT, int OCB>
__global__ __launch_bounds__(256)
void off_conv_sg_kernel(const float* __restrict__ in, const float* __restrict__ wgt,
                        const float* __restrict__ bias, float* __restrict__ out) {
    constexpr int KK = K*K;
    const int nOB = COUT / OCB;
    const int b   = blockIdx.x / nOB;
    const int oc0 = (blockIdx.x % nOB) * OCB;
    const int x   = threadIdx.x;
    const int h   = blockIdx.y*4 + threadIdx.y;

    float acc[OCB];
    #pragma unroll
    for (int o = 0; o < OCB; ++o) acc[o] = bias[oc0+o];

    const float* inb = in + (size_t)b*CC*HW;
    const float* wb  = wgt + (size_t)oc0*CC*KK;

    for (int ic = 0; ic < CC; ++ic) {
        const float* inp = inb + ic*HW;
        const float* wp  = wb + ic*KK;
        #pragma unroll
        for (int ky = 0; ky < K; ++ky) {
            const int  y  = h + ky*DIL - PAD;
            const bool yv = (y >= 0) && (y < HH);
            const int  yc = yv ? y : 0;
            const float* row = inp + yc*WW;
            #pragma unroll
            for (int kx = 0; kx < K; ++kx) {
                const int  xx = x + kx*DIL - PAD;
                const bool v  = yv && (xx >= 0) && (xx < WW);
                const int  xc = (xx < 0) ? 0 : ((xx >= WW) ? (WW-1) : xx);
                float val = row[xc];
                val = v ? val : 0.f;
                const int t = ky*K + kx;
                #pragma unroll
                for (int o = 0; o < OCB; ++o)
                    acc[o] += wp[(size_t)o*CC*KK + t] * val;
            }
        }
    }

    if (x >= WW) return;
    #pragma unroll
    for (int o = 0; o < OCB; ++o)
        out[((size_t)b*COUT + oc0 + o)*HW + h*WW + x] = acc[o];
}

template<int K, int DIL, int PAD>
__global__ __launch_bounds__(64)
void deform_dw_full_kernel(const float* __restrict__ in, const float* __restrict__ off,
                           const float* __restrict__ dw, float* __restrict__ out) {
    constexpr int KK = K*K;
    const int idx = blockIdx.x*64 + threadIdx.x;
    const int x = idx % WW;
    const int h = (idx / WW) % HH;
    const int c = (idx / HW) % CC;
    const int b = idx / (CC*HW);

    const float* inp  = in  + ((size_t)b*CC + c)*HW;
    const float* offp = off + (size_t)b*(2*KK)*HW + h*WW + x;
    const float* dwp  = dw  + c*KK;

    float acc = 0.f;
    #pragma unroll 7
    for (int k = 0; k < KK; ++k) {
        const float dy = offp[(2*k  )*HW];
        const float dx = offp[(2*k+1)*HW];
        const float py = (float)(h + (k/K)*DIL - PAD) + dy;
        const float px = (float)(x + (k%K)*DIL - PAD) + dx;
        const float y0f = floorf(py), x0f = floorf(px);
        const float wy1 = py - y0f,  wx1 = px - x0f;
        const float wy0 = 1.f - wy1, wx0 = 1.f - wx1;
        const int y0 = (int)y0f, x0 = (int)x0f;

        const int y0c = min(max(y0,   0), HH-1);
        const int y1c = min(max(y0+1, 0), HH-1);
        const int x0c = min(max(x0,   0), WW-1);
        const int x1c = min(max(x0+1, 0), WW-1);
        const float my0 = (y0   >= 0 && y0   < HH) ? 1.f : 0.f;
        const float my1 = (y0+1 >= 0 && y0+1 < HH) ? 1.f : 0.f;
        const float mx0 = (x0   >= 0 && x0   < WW) ? 1.f : 0.f;
        const float mx1 = (x0+1 >= 0 && x0+1 < WW) ? 1.f : 0.f;

        const float v00 = inp[y0c*WW + x0c];
        const float v01 = inp[y0c*WW + x1c];
        const float v10 = inp[y1c*WW + x0c];
        const float v11 = inp[y1c*WW + x1c];

        const float gx0 = wx0*mx0, gx1 = wx1*mx1;
        const float s = (v00*gx0 + v01*gx1) * (wy0*my0)
                      + (v10*gx0 + v11*gx1) * (wy1*my1);
        acc += s * dwp[k];
    }
    out[idx] = acc;
}

__global__ __launch_bounds__(256)
void pw_mul_kernel(const float* __restrict__ x, const float* __restrict__ a2,
                   const float* __restrict__ pw, const float* __restrict__ pb,
                   float* __restrict__ out) {
    constexpr int HW4 = HW/4;
    const int t = blockIdx.x*256 + threadIdx.x;
    if (t >= BB*CC*HW4) return;
    const int sp4 = t % HW4;
    const int oc  = (t / HW4) % CC;
    const int b   = t / (CC*HW4);

    const float4* ap = (const float4*)(a2 + (size_t)b*CC*HW) + sp4;
    const float4* wp4 = (const float4*)(pw + oc*CC);
    const float pbv = pb[oc];
    float4 acc = make_float4(pbv, pbv, pbv, pbv);
    #pragma unroll 4
    for (int ic4 = 0; ic4 < CC/4; ++ic4) {
        const float4 w = wp4[ic4];
        float4 a0 = ap[(ic4*4+0)*HW4];
        float4 a1 = ap[(ic4*4+1)*HW4];
        float4 a2v = ap[(ic4*4+2)*HW4];
        float4 a3 = ap[(ic4*4+3)*HW4];
        acc.x += w.x*a0.x + w.y*a1.x + w.z*a2v.x + w.w*a3.x;
        acc.y += w.x*a0.y + w.y*a1.y + w.z*a2v.y + w.w*a3.y;
        acc.z += w.x*a0.z + w.y*a1.z + w.z*a2v.z + w.w*a3.z;
        acc.w += w.x*a0.w + w.y*a1.w + w.z*a2v.w + w.w*a3.w;
    }
    const float4 xv = ((const float4*)x)[t];
    float4 r;
    r.x = xv.x*acc.x; r.y = xv.y*acc.y; r.z = xv.z*acc.z; r.w = xv.w*acc.w;
    ((float4*)out)[t] = r;
}

extern "C" void kernel_launch(void* const* d_in, const int* in_sizes, int n_in,
                              void* d_out, int out_size, void* d_ws, size_t ws_size,
                              hipStream_t stream) {
    const float* x      = (const float*)d_in[0];
    const float* off_w1 = (const float*)d_in[1];
    const float* off_b1 = (const float*)d_in[2];
    const float* dw_w1  = (const float*)d_in[3];
    const float* off_w2 = (const float*)d_in[4];
    const float* off_b2 = (const float*)d_in[5];
    const float* dw_w2  = (const float*)d_in[6];
    const float* pw_w   = (const float*)d_in[7];
    const float* pw_b   = (const float*)d_in[8];
    float* out = (float*)d_out;

    const size_t nF    = (size_t)BB*CC*HW;
    const size_t attnB = nF*sizeof(float);
    const size_t off2B = (size_t)BB*98*HW*sizeof(float);   // fallback layout
    const size_t offTB = (size_t)BB*HW*112*sizeof(float);  // transposed offsets
    const size_t chB   = (size_t)BB*HW*64*sizeof(u16);
    char* ws = (char*)d_ws;

    const int n    = (int)nF;
    const int dbl  = n/64;
    const int pbl  = (n/4 + 255)/256;
    dim3 cblk(64,4);
    dim3 rgrd1(BB*(50/5), HH/4);
    dim3 rgrd2(BB*(98/7), HH/4);
    dim3 cgrd1(TGRID, 2);                    // conv1: 64 n / 32 per block
    dim3 cgrd2(TGRID, 4);                    // conv2: 128 n / 32 per block
    dim3 pgrd(TGRID, 4);                     // pw
    const int dgrid = BB*HW/8;               // 1568 (8 pixels per block)

    const size_t oOFF  = 0;
    const size_t oXT   = oOFF + offTB;
    const size_t oA1T  = oXT  + chB;
    const size_t oA2T  = oA1T + chB;
    const size_t oW1   = oA2T + chB;
    const size_t oW2   = oW1  + (size_t)R1*2;
    const size_t oPWT  = oW2  + (size_t)R2*2;
    const size_t oDW1  = oPWT + (size_t)R3*2;
    const size_t oDW2  = oDW1 + (size_t)R4*4;
    const size_t TOT   = oDW2 + (size_t)R5*4;   // ~11.47 MB

    if (ws_size >= TOT) {
        float* off_buf = (float*)(ws + oOFF);
        u16*   xT      = (u16*)(ws + oXT);
        u16*   a1T     = (u16*)(ws + oA1T);
        u16*   a2T     = (u16*)(ws + oA2T);
        u16*   w2t1    = (u16*)(ws + oW1);
        u16*   w2t2    = (u16*)(ws + oW2);
        u16*   pwT     = (u16*)(ws + oPWT);
        float* dwT1    = (float*)(ws + oDW1);
        float* dwT2    = (float*)(ws + oDW2);

        prep_tr_kernel<<<TGRID + (PREPN+255)/256, 256, 0, stream>>>(
            x, off_w1, off_w2, pw_w, dw_w1, dw_w2,
            xT, w2t1, w2t2, pwT, dwT1, dwT2);

        conv_mfma_lds_kernel<5,1,2,50,64,64,2><<<cgrd1, 256, 0, stream>>>(xT, w2t1, off_b1, off_buf);
        deform_cl_kernel<5,1,2,64><<<dgrid, 256, 0, stream>>>(xT, off_buf, dwT1, a1T);

        conv_mfma_lds_kernel<7,3,9,98,128,112,2><<<cgrd2, 256, 0, stream>>>(a1T, w2t2, off_b2, off_buf);
        deform_cl_kernel<7,3,9,112><<<dgrid, 256, 0, stream>>>(a1T, off_buf, dwT2, a2T);

        pw_mfma_kernel<<<pgrd, 256, 0, stream>>>(a2T, pwT, pw_b, x, out);
    } else if (ws_size >= off2B + attnB) {
        float* off_buf = (float*)ws;
        float* attn1   = (float*)d_out;
        float* attn2   = (float*)(ws + off2B);
        off_conv_sg_kernel<5,1,2,50,5><<<rgrd1, cblk, 0, stream>>>(x, off_w1, off_b1, off_buf);
        deform_dw_full_kernel<5,1,2><<<dbl, 64, 0, stream>>>(x, off_buf, dw_w1, attn1);
        off_conv_sg_kernel<7,3,9,98,7><<<rgrd2, cblk, 0, stream>>>(attn1, off_w2, off_b2, off_buf);
        deform_dw_full_kernel<7,3,9><<<dbl, 64, 0, stream>>>(attn1, off_buf, dw_w2, attn2);
        pw_mul_kernel<<<pbl, 256, 0, stream>>>(x, attn2, pw_w, pw_b, out);
    } else {
        float* attn1 = (float*)d_out;
        float* attn2 = (float*)ws;
        float* off1  = (float*)ws;
        off_conv_sg_kernel<5,1,2,50,5><<<rgrd1, cblk, 0, stream>>>(x, off_w1, off_b1, off1);
        deform_dw_full_kernel<5,1,2><<<dbl, 64, 0, stream>>>(x, off1, dw_w1, attn1);
        float* off2 = (float*)(ws + attnB);
        off_conv_sg_kernel<7,3,9,98,7><<<rgrd2, cblk, 0, stream>>>(attn1, off_w2, off_b2, off2);
        deform_dw_full_kernel<7,3,9><<<dbl, 64, 0, stream>>>(attn1, off2, dw_w2, attn2);
        pw_mul_kernel<<<pbl, 256, 0, stream>>>(x, attn2, pw_w, pw_b, out);
    }
}

// Round 11
// 153.180 us; speedup vs baseline: 1.3968x; 1.0148x over previous
//
#include <hip/hip_runtime.h>

// Problem constants (from reference setup_inputs)
#define BB 4
#define CC 64
#define HH 56
#define WW 56
#define HW (HH*WW)

typedef unsigned short u16;
typedef unsigned int u32;
typedef __attribute__((ext_vector_type(8))) short bf16x8;
typedef __attribute__((ext_vector_type(4))) float f32x4;

__device__ __forceinline__ u16 f2bf(float f) {
    union { float f; unsigned u; } c; c.f = f;
    unsigned u = c.u;
    u = (u + 0x7FFFu + ((u >> 16) & 1u)) >> 16;   // RNE
    return (u16)u;
}
__device__ __forceinline__ float lo_f(u32 u) {   // bf16 pair -> lo fp32
    union { unsigned u; float f; } c; c.u = u << 16; return c.f;
}
__device__ __forceinline__ float hi_f(u32 u) {   // bf16 pair -> hi fp32
    union { unsigned u; float f; } c; c.u = u & 0xffff0000u; return c.f;
}

// ---------------------------------------------------------------------------
// Fused prep + input transpose in ONE launch (R5 baseline).
// ---------------------------------------------------------------------------
#define R1 102400
#define R2 401408
#define R3 4096
#define R4 1600
#define R5 3136
#define TGRID (BB*(HW/64))          // 196
#define PREPN (R1+R2+R3+R4+R5)
__global__ __launch_bounds__(256)
void prep_tr_kernel(const float* __restrict__ x,
                    const float* __restrict__ ow1, const float* __restrict__ ow2,
                    const float* __restrict__ pw,  const float* __restrict__ dw1,
                    const float* __restrict__ dw2,
                    u16* __restrict__ xT,
                    u16* __restrict__ w2t1, u16* __restrict__ w2t2,
                    u16* __restrict__ pwT, float* __restrict__ dwT1,
                    float* __restrict__ dwT2) {
    __shared__ u16 tile[64][72];
    const int t = threadIdx.x;
    if (blockIdx.x < TGRID) {
        const int blk = blockIdx.x;
        const int b   = blk / (HW/64);
        const int p0  = (blk % (HW/64))*64;
        const int px  = t & 63, icq = t >> 6;
        const float* ip = x + ((size_t)b*CC + icq*16)*HW + p0 + px;
        #pragma unroll
        for (int i = 0; i < 16; ++i)
            tile[px][icq*16 + i] = f2bf(ip[(size_t)i*HW]);
        __syncthreads();
        const int px2 = t >> 2, g = t & 3;
        u16* op = xT + ((size_t)b*HW + p0 + px2)*64 + g*16;
        const uint4* s = (const uint4*)&tile[px2][g*16];
        ((uint4*)op)[0] = s[0];
        ((uint4*)op)[1] = s[1];
        return;
    }
    const int i = (blockIdx.x - TGRID)*256 + t;
    if (i < R1) {
        const int ic = i & 63, n = (i >> 6) & 63, tap = i >> 12;
        w2t1[i] = f2bf((n < 50) ? ow1[((size_t)n*64 + ic)*25 + tap] : 0.f);
    } else if (i < R1+R2) {
        const int j = i - R1;
        const int ic = j & 63, n = (j >> 6) & 127, tap = j >> 13;
        w2t2[j] = f2bf((n < 98) ? ow2[((size_t)n*64 + ic)*49 + tap] : 0.f);
    } else if (i < R1+R2+R3) {
        const int j = i - (R1+R2);
        pwT[j] = f2bf(pw[j]);
    } else if (i < R1+R2+R3+R4) {
        const int j = i - (R1+R2+R3);
        const int c = j & 63, k = j >> 6;
        dwT1[j] = dw1[c*25 + k];
    } else if (i < R1+R2+R3+R4+R5) {
        const int j = i - (R1+R2+R3+R4);
        const int c = j & 63, k = j >> 6;
        dwT2[j] = dw2[c*49 + k];
    }
}

__device__ __forceinline__ uint4 selz(bool v, uint4 a) {
    const uint4 z = make_uint4(0,0,0,0);
    return v ? a : z;
}

// ---------------------------------------------------------------------------
// LDS-staged MFMA implicit-GEMM conv (exact R5 form, measured-best total).
// NTW=2, transposed output (B,HW,NPAD) fp32.
// ---------------------------------------------------------------------------
template<int K, int DIL, int PAD, int COUT, int NP, int NPAD, int NTW>
__global__ __launch_bounds__(256, 4)
void conv_mfma_lds_kernel(const u16* __restrict__ xT, const u16* __restrict__ w2t,
                          const float* __restrict__ bias, float* __restrict__ out) {
    constexpr int KK = K*K;
    constexpr int BROWS = 16*NTW;
    __shared__ u16 Ab[2][64*64];
    __shared__ u16 Bb[2][BROWS*64];

    const int nm   = HW/64;                       // 49
    const int b    = blockIdx.x / nm;
    const int p0   = (blockIdx.x % nm)*64;
    const int nt0  = blockIdx.y;
    const int t    = threadIdx.x;
    const int wave = t >> 6;
    const int lane = t & 63;

    const int spx = t >> 3;                       // 0..31
    const int sc  = t & 7;                        // chunk 0..7
    const int pA  = p0 + spx;
    const int pB  = p0 + spx + 32;
    const int pyA = pA / WW, pxA = pA % WW;
    const int pyB = pB / WW, pxB = pB % WW;
    const u16* xb = xT + (size_t)b*HW*64;
    const int sslotA = ((sc + spx) & 7)*8;
    const int bn  = t >> 3;                       // 0..31
    const int bslot = ((sc + bn) & 7)*8;
    const u16* wbase = w2t + (size_t)nt0*BROWS*64;

    const int r = lane & 15, quad = lane >> 4;
    const int mloc = wave*16 + r;
    const int arow = mloc*64;
    const int a0s = ((quad     + mloc) & 7)*8;
    const int a1s = ((quad + 4 + mloc) & 7)*8;
    const int b0s = ((quad     + r) & 7)*8;
    const int b1s = ((quad + 4 + r) & 7)*8;

    f32x4 acc[NTW];
    #pragma unroll
    for (int h = 0; h < NTW; ++h) acc[h] = (f32x4){0.f,0.f,0.f,0.f};
    const uint4 z4 = make_uint4(0,0,0,0);

    auto LD = [&](int tap, uint4& a0, uint4& a1, bool& va, bool& vb, uint4& bb) {
        const int dyy = (tap/K)*DIL - PAD;
        const int dxx = (tap%K)*DIL - PAD;
        const int off = dyy*WW + dxx;
        {
            const int yy = pyA + dyy, xx = pxA + dxx;
            va = ((unsigned)yy < (unsigned)HH) && ((unsigned)xx < (unsigned)WW);
            a0 = *(const uint4*)(xb + (size_t)(va ? (pA + off) : 0)*64 + sc*8);
        }
        {
            const int yy = pyB + dyy, xx = pxB + dxx;
            vb = ((unsigned)yy < (unsigned)HH) && ((unsigned)xx < (unsigned)WW);
            a1 = *(const uint4*)(xb + (size_t)(vb ? (pB + off) : 0)*64 + sc*8);
        }
        if (BROWS == 32 || bn < BROWS)
            bb = *(const uint4*)(wbase + ((size_t)tap*NP + bn)*64 + sc*8);
    };

    uint4 rA0 = z4, rA1 = z4, rB = z4;
    bool v0 = false, v1 = false;
    LD(0, rA0, rA1, v0, v1, rB);

    #pragma unroll
    for (int tap = 0; tap < KK; ++tap) {
        uint4 nA0 = z4, nA1 = z4, nB = z4;
        bool nv0 = false, nv1 = false;
        if (tap + 1 < KK) LD(tap + 1, nA0, nA1, nv0, nv1, nB);

        u16* A  = &Ab[tap & 1][0];
        u16* Bq = &Bb[tap & 1][0];
        *(uint4*)(A + spx*64      + sslotA) = selz(v0, rA0);
        *(uint4*)(A + (spx+32)*64 + sslotA) = selz(v1, rA1);
        if (BROWS == 32 || bn < BROWS) *(uint4*)(Bq + bn*64 + bslot) = rB;
        __syncthreads();

        const bf16x8 av0 = *(const bf16x8*)(A + arow + a0s);
        const bf16x8 av1 = *(const bf16x8*)(A + arow + a1s);
        #pragma unroll
        for (int h = 0; h < NTW; ++h) {
            const int brow = (h*16 + r)*64;
            const bf16x8 bv0 = *(const bf16x8*)(Bq + brow + b0s);
            const bf16x8 bv1 = *(const bf16x8*)(Bq + brow + b1s);
            acc[h] = __builtin_amdgcn_mfma_f32_16x16x32_bf16(av0, bv0, acc[h], 0, 0, 0);
            acc[h] = __builtin_amdgcn_mfma_f32_16x16x32_bf16(av1, bv1, acc[h], 0, 0, 0);
        }

        rA0 = nA0; rA1 = nA1; rB = nB; v0 = nv0; v1 = nv1;
    }

    #pragma unroll
    for (int h = 0; h < NTW; ++h) {
        const int n = nt0*BROWS + h*16 + r;
        if (n < COUT) {
            const float bv = bias[n];
            float* op = out + ((size_t)b*HW + p0 + wave*16 + quad*4)*NPAD + n;
            #pragma unroll
            for (int r2 = 0; r2 < 4; ++r2) op[(size_t)r2*NPAD] = acc[h][r2] + bv;
        }
    }
}

// ---------------------------------------------------------------------------
// Two-phase deform, 2 channels/lane, R10 deepened software pipeline
// (measured-best): corners 2 taps ahead (ring-of-3), addresses 3 ahead.
// Used for deform1 (K=5) which writes a1T.
// ---------------------------------------------------------------------------
template<int K, int DIL, int PAD, int NPAD>
__global__ __launch_bounds__(256)
void deform_cl_kernel(const u16* __restrict__ inT, const float* __restrict__ offT,
                      const float* __restrict__ dwT, u16* __restrict__ outT) {
    constexpr int KK = K*K;
    __shared__ float4 swt[8][KK];
    __shared__ int4   sat[8][KK];
    __shared__ float  sdw[KK*64];

    const int t = threadIdx.x;
    const int nb8 = (BB*HW/8) >> 3;               // 196
    const int blk0 = blockIdx.x;
    const int blk = (blk0 & 7)*nb8 + (blk0 >> 3); // XCD-contiguous pixels
    const int p0 = blk*8;
    const int b  = p0 / HW;                       // 8 | HW -> same batch
    const int pl0 = p0 - b*HW;

    for (int i = t; i < KK*64; i += 256) sdw[i] = dwT[i];

    for (int i = t; i < 8*KK; i += 256) {
        const int pix = i / KK, k = i - pix*KK;
        const int pl  = pl0 + pix;
        const int h = pl / WW, w = pl % WW;
        const float* orow = offT + ((size_t)b*HW + pl)*NPAD;
        const float dy = orow[2*k];
        const float dx = orow[2*k+1];
        const float py = (float)(h + (k/K)*DIL - PAD) + dy;
        const float px = (float)(w + (k%K)*DIL - PAD) + dx;
        const float y0f = floorf(py), x0f = floorf(px);
        const float wy1 = py - y0f,  wx1 = px - x0f;
        const float wy0 = 1.f - wy1, wx0 = 1.f - wx1;
        const int y0 = (int)y0f, x0 = (int)x0f;

        const int y0c = min(max(y0,   0), HH-1);
        const int y1c = min(max(y0+1, 0), HH-1);
        const int x0c = min(max(x0,   0), WW-1);
        const int x1c = min(max(x0+1, 0), WW-1);
        const float gy0 = wy0 * ((y0   >= 0 && y0   < HH) ? 1.f : 0.f);
        const float gy1 = wy1 * ((y0+1 >= 0 && y0+1 < HH) ? 1.f : 0.f);
        const float gx0 = wx0 * ((x0   >= 0 && x0   < WW) ? 1.f : 0.f);
        const float gx1 = wx1 * ((x0+1 >= 0 && x0+1 < WW) ? 1.f : 0.f);

        swt[pix][k] = make_float4(gy0*gx0, gy0*gx1, gy1*gx0, gy1*gx1);
        const int r0 = y0c*WW, r1 = y1c*WW;
        sat[pix][k] = make_int4((r0 + x0c) << 7, (r0 + x1c) << 7,
                                (r1 + x0c) << 7, (r1 + x1c) << 7);
    }
    __syncthreads();

    const int wave = t >> 6, lane = t & 63;
    const int pixl = 2*wave + (lane >> 5);        // 0..7 (half-wave = pixel)
    const int chp  = lane & 31;                   // channel pair 0..31
    const char* ib = (const char*)(inT + (size_t)b*HW*64) + chp*4;

    float accx = 0.f, accy = 0.f;

    int4   av[4];
    float4 wv[2];
    float2 dv[2];
    u32 c00[3], c01[3], c10[3], c11[3];

    av[0] = sat[pixl][0];
    if (KK > 1) av[1] = sat[pixl][1];
    if (KK > 2) av[2] = sat[pixl][2];
    wv[0] = swt[pixl][0];
    dv[0] = *(const float2*)&sdw[2*chp];
    c00[0] = *(const u32*)(ib + av[0].x);
    c01[0] = *(const u32*)(ib + av[0].y);
    c10[0] = *(const u32*)(ib + av[0].z);
    c11[0] = *(const u32*)(ib + av[0].w);
    if (KK > 1) {
        c00[1] = *(const u32*)(ib + av[1].x);
        c01[1] = *(const u32*)(ib + av[1].y);
        c10[1] = *(const u32*)(ib + av[1].z);
        c11[1] = *(const u32*)(ib + av[1].w);
    }

    #pragma unroll
    for (int k = 0; k < KK; ++k) {
        if (k + 3 < KK) av[(k+3)&3] = sat[pixl][k+3];
        if (k + 2 < KK) {
            const int4 a = av[(k+2)&3];
            c00[(k+2)%3] = *(const u32*)(ib + a.x);
            c01[(k+2)%3] = *(const u32*)(ib + a.y);
            c10[(k+2)%3] = *(const u32*)(ib + a.z);
            c11[(k+2)%3] = *(const u32*)(ib + a.w);
        }
        if (k + 1 < KK) {
            wv[(k+1)&1] = swt[pixl][k+1];
            dv[(k+1)&1] = *(const float2*)&sdw[(k+1)*64 + 2*chp];
        }
        const float4 w = wv[k&1];
        const u32 u00 = c00[k%3], u01 = c01[k%3], u10 = c10[k%3], u11 = c11[k%3];
        const float sx = lo_f(u00)*w.x + lo_f(u01)*w.y + lo_f(u10)*w.z + lo_f(u11)*w.w;
        const float sy = hi_f(u00)*w.x + hi_f(u01)*w.y + hi_f(u10)*w.z + hi_f(u11)*w.w;
        const float2 d = dv[k&1];
        accx += sx * d.x;
        accy += sy * d.y;
    }

    const u32 o = (u32)f2bf(accx) | ((u32)f2bf(accy) << 16);
    *(u32*)((char*)outT + (size_t)(p0 + pixl)*128 + chp*4) = o;
}

// ---------------------------------------------------------------------------
// FUSED deform2 + pointwise + residual multiply. Tap loop identical to
// deform_cl_kernel (R10 pipeline). Epilogue: barrier -> write attn bf16 into
// LDS aliasing the dead swt buffer (no LDS growth, occupancy unchanged at
// 6 blk/24 waves per CU) -> barrier -> each wave runs pw_mfma's exact
// fragment sequence (2x mfma 16x16x32, K-chunk order preserved) for its
// 16-n tile; A-rows 8..15 are garbage landing only in discarded C-rows
// (MFMA rows independent). quad<2 lanes write out = x*(acc+bias).
// Saves the pw launch + a2T round-trip; bit-identical output.
// ---------------------------------------------------------------------------
template<int K, int DIL, int PAD, int NPAD>
__global__ __launch_bounds__(256)
void deform_pw_kernel(const u16* __restrict__ inT, const float* __restrict__ offT,
                      const float* __restrict__ dwT, const u16* __restrict__ pwT,
                      const float* __restrict__ pb, const float* __restrict__ x,
                      float* __restrict__ out) {
    constexpr int KK = K*K;
    __shared__ float4 swt[8][KK];
    __shared__ int4   sat[8][KK];
    __shared__ float  sdw[KK*64];

    const int t = threadIdx.x;
    const int nb8 = (BB*HW/8) >> 3;               // 196
    const int blk0 = blockIdx.x;
    const int blk = (blk0 & 7)*nb8 + (blk0 >> 3); // XCD-contiguous pixels
    const int p0 = blk*8;
    const int b  = p0 / HW;                       // 8 | HW -> same batch
    const int pl0 = p0 - b*HW;

    for (int i = t; i < KK*64; i += 256) sdw[i] = dwT[i];

    for (int i = t; i < 8*KK; i += 256) {
        const int pix = i / KK, k = i - pix*KK;
        const int pl  = pl0 + pix;
        const int h = pl / WW, w = pl % WW;
        const float* orow = offT + ((size_t)b*HW + pl)*NPAD;
        const float dy = orow[2*k];
        const float dx = orow[2*k+1];
        const float py = (float)(h + (k/K)*DIL - PAD) + dy;
        const float px = (float)(w + (k%K)*DIL - PAD) + dx;
        const float y0f = floorf(py), x0f = floorf(px);
        const float wy1 = py - y0f,  wx1 = px - x0f;
        const float wy0 = 1.f - wy1, wx0 = 1.f - wx1;
        const int y0 = (int)y0f, x0 = (int)x0f;

        const int y0c = min(max(y0,   0), HH-1);
        const int y1c = min(max(y0+1, 0), HH-1);
        const int x0c = min(max(x0,   0), WW-1);
        const int x1c = min(max(x0+1, 0), WW-1);
        const float gy0 = wy0 * ((y0   >= 0 && y0   < HH) ? 1.f : 0.f);
        const float gy1 = wy1 * ((y0+1 >= 0 && y0+1 < HH) ? 1.f : 0.f);
        const float gx0 = wx0 * ((x0   >= 0 && x0   < WW) ? 1.f : 0.f);
        const float gx1 = wx1 * ((x0+1 >= 0 && x0+1 < WW) ? 1.f : 0.f);

        swt[pix][k] = make_float4(gy0*gx0, gy0*gx1, gy1*gx0, gy1*gx1);
        const int r0 = y0c*WW, r1 = y1c*WW;
        sat[pix][k] = make_int4((r0 + x0c) << 7, (r0 + x1c) << 7,
                                (r1 + x0c) << 7, (r1 + x1c) << 7);
    }
    __syncthreads();

    const int wave = t >> 6, lane = t & 63;
    const int pixl = 2*wave + (lane >> 5);        // 0..7 (half-wave = pixel)
    const int chp  = lane & 31;                   // channel pair 0..31
    const char* ib = (const char*)(inT + (size_t)b*HW*64) + chp*4;

    float accx = 0.f, accy = 0.f;

    int4   av[4];
    float4 wv[2];
    float2 dv[2];
    u32 c00[3], c01[3], c10[3], c11[3];

    av[0] = sat[pixl][0];
    if (KK > 1) av[1] = sat[pixl][1];
    if (KK > 2) av[2] = sat[pixl][2];
    wv[0] = swt[pixl][0];
    dv[0] = *(const float2*)&sdw[2*chp];
    c00[0] = *(const u32*)(ib + av[0].x);
    c01[0] = *(const u32*)(ib + av[0].y);
    c10[0] = *(const u32*)(ib + av[0].z);
    c11[0] = *(const u32*)(ib + av[0].w);
    if (KK > 1) {
        c00[1] = *(const u32*)(ib + av[1].x);
        c01[1] = *(const u32*)(ib + av[1].y);
        c10[1] = *(const u32*)(ib + av[1].z);
        c11[1] = *(const u32*)(ib + av[1].w);
    }

    #pragma unroll
    for (int k = 0; k < KK; ++k) {
        if (k + 3 < KK) av[(k+3)&3] = sat[pixl][k+3];
        if (k + 2 < KK) {
            const int4 a = av[(k+2)&3];
            c00[(k+2)%3] = *(const u32*)(ib + a.x);
            c01[(k+2)%3] = *(const u32*)(ib + a.y);
            c10[(k+2)%3] = *(const u32*)(ib + a.z);
            c11[(k+2)%3] = *(const u32*)(ib + a.w);
        }
        if (k + 1 < KK) {
            wv[(k+1)&1] = swt[pixl][k+1];
            dv[(k+1)&1] = *(const float2*)&sdw[(k+1)*64 + 2*chp];
        }
        const float4 w = wv[k&1];
        const u32 u00 = c00[k%3], u01 = c01[k%3], u10 = c10[k%3], u11 = c11[k%3];
        const float sx = lo_f(u00)*w.x + lo_f(u01)*w.y + lo_f(u10)*w.z + lo_f(u11)*w.w;
        const float sy = hi_f(u00)*w.x + hi_f(u01)*w.y + hi_f(u10)*w.z + hi_f(u11)*w.w;
        const float2 d = dv[k&1];
        accx += sx * d.x;
        accy += sy * d.y;
    }

    // ---- fused pw epilogue ----
    __syncthreads();                              // all waves done reading swt/sat
    u16* att = (u16*)&swt[0][0];                  // alias dead swt buffer (2KB used)
    const u32 o = (u32)f2bf(accx) | ((u32)f2bf(accy) << 16);
    *(u32*)((char*)att + pixl*128 + chp*4) = o;   // att[pix][ch] bf16, rows 0..7
    __syncthreads();

    const int r = lane & 15, quad = lane >> 4;
    f32x4 pacc = (f32x4){0.f,0.f,0.f,0.f};
    #pragma unroll
    for (int ks = 0; ks < 2; ++ks) {
        const bf16x8 pav = *(const bf16x8*)(att + r*64 + ks*32 + quad*8);
        const bf16x8 pbv = *(const bf16x8*)(pwT + ((size_t)(wave*16 + r))*64 + ks*32 + quad*8);
        pacc = __builtin_amdgcn_mfma_f32_16x16x32_bf16(pav, pbv, pacc, 0, 0, 0);
    }
    if (quad < 2) {                               // C rows = pixels quad*4+r2 (0..7 valid)
        const int n = wave*16 + r;
        const float bvb = pb[n];
        const size_t base = ((size_t)b*CC + n)*HW + pl0 + quad*4;
        #pragma unroll
        for (int r2 = 0; r2 < 4; ++r2)
            out[base + r2] = x[base + r2] * (pacc[r2] + bvb);
    }
}

// ======================= fallback fp32 kernels (low ws) =====================
template<int K, int DIL, int PAD, int COUT, int OCB>
__global__ __launch_bounds__(256)
void off_conv_sg_kernel(const float* __restrict__ in, const float* __restrict__ wgt,
                        const float* __restrict__ bias, float* __restrict__ out) {
    constexpr int KK = K*K;
    const int nOB = COUT / OCB;
    const int b   = blockIdx.x / nOB;
    const int oc0 = (blockIdx.x % nOB) * OCB;
    const int x   = threadIdx.x;
    const int h   = blockIdx.y*4 + threadIdx.y;

    float acc[OCB];
    #pragma unroll
    for (int o = 0; o < OCB; ++o) acc[o] = bias[oc0+o];

    const float* inb = in + (size_t)b*CC*HW;
    const float* wb  = wgt + (size_t)oc0*CC*KK;

    for (int ic = 0; ic < CC; ++ic) {
        const float* inp = inb + ic*HW;
        const float* wp  = wb + ic*KK;
        #pragma unroll
        for (int ky = 0; ky < K; ++ky) {
            const int  y  = h + ky*DIL - PAD;
            const bool yv = (y >= 0) && (y < HH);
            const int  yc = yv ? y : 0;
            const float* row = inp + yc*WW;
            #pragma unroll
            for (int kx = 0; kx < K; ++kx) {
                const int  xx = x + kx*DIL - PAD;
                const bool v  = yv && (xx >= 0) && (xx < WW);
                const int  xc = (xx < 0) ? 0 : ((xx >= WW) ? (WW-1) : xx);
                float val = row[xc];
                val = v ? val : 0.f;
                const int t = ky*K + kx;
                #pragma unroll
                for (int o = 0; o < OCB; ++o)
                    acc[o] += wp[(size_t)o*CC*KK + t] * val;
            }
        }
    }

    if (x >= WW) return;
    #pragma unroll
    for (int o = 0; o < OCB; ++o)
        out[((size_t)b*COUT + oc0 + o)*HW + h*WW + x] = acc[o];
}

template<int K, int DIL, int PAD>
__global__ __launch_bounds__(64)
void deform_dw_full_kernel(const float* __restrict__ in, const float* __restrict__ off,
                           const float* __restrict__ dw, float* __restrict__ out) {
    constexpr int KK = K*K;
    const int idx = blockIdx.x*64 + threadIdx.x;
    const int x = idx % WW;
    const int h = (idx / WW) % HH;
    const int c = (idx / HW) % CC;
    const int b = idx / (CC*HW);

    const float* inp  = in  + ((size_t)b*CC + c)*HW;
    const float* offp = off + (size_t)b*(2*KK)*HW + h*WW + x;
    const float* dwp  = dw  + c*KK;

    float acc = 0.f;
    #pragma unroll 7
    for (int k = 0; k < KK; ++k) {
        const float dy = offp[(2*k  )*HW];
        const float dx = offp[(2*k+1)*HW];
        const float py = (float)(h + (k/K)*DIL - PAD) + dy;
        const float px = (float)(x + (k%K)*DIL - PAD) + dx;
        const float y0f = floorf(py), x0f = floorf(px);
        const float wy1 = py - y0f,  wx1 = px - x0f;
        const float wy0 = 1.f - wy1, wx0 = 1.f - wx1;
        const int y0 = (int)y0f, x0 = (int)x0f;

        const int y0c = min(max(y0,   0), HH-1);
        const int y1c = min(max(y0+1, 0), HH-1);
        const int x0c = min(max(x0,   0), WW-1);
        const int x1c = min(max(x0+1, 0), WW-1);
        const float my0 = (y0   >= 0 && y0   < HH) ? 1.f : 0.f;
        const float my1 = (y0+1 >= 0 && y0+1 < HH) ? 1.f : 0.f;
        const float mx0 = (x0   >= 0 && x0   < WW) ? 1.f : 0.f;
        const float mx1 = (x0+1 >= 0 && x0+1 < WW) ? 1.f : 0.f;

        const float v00 = inp[y0c*WW + x0c];
        const float v01 = inp[y0c*WW + x1c];
        const float v10 = inp[y1c*WW + x0c];
        const float v11 = inp[y1c*WW + x1c];

        const float gx0 = wx0*mx0, gx1 = wx1*mx1;
        const float s = (v00*gx0 + v01*gx1) * (wy0*my0)
                      + (v10*gx0 + v11*gx1) * (wy1*my1);
        acc += s * dwp[k];
    }
    out[idx] = acc;
}

__global__ __launch_bounds__(256)
void pw_mul_kernel(const float* __restrict__ x, const float* __restrict__ a2,
                   const float* __restrict__ pw, const float* __restrict__ pb,
                   float* __restrict__ out) {
    constexpr int HW4 = HW/4;
    const int t = blockIdx.x*256 + threadIdx.x;
    if (t >= BB*CC*HW4) return;
    const int sp4 = t % HW4;
    const int oc  = (t / HW4) % CC;
    const int b   = t / (CC*HW4);

    const float4* ap = (const float4*)(a2 + (size_t)b*CC*HW) + sp4;
    const float4* wp4 = (const float4*)(pw + oc*CC);
    const float pbv = pb[oc];
    float4 acc = make_float4(pbv, pbv, pbv, pbv);
    #pragma unroll 4
    for (int ic4 = 0; ic4 < CC/4; ++ic4) {
        const float4 w = wp4[ic4];
        float4 a0 = ap[(ic4*4+0)*HW4];
        float4 a1 = ap[(ic4*4+1)*HW4];
        float4 a2v = ap[(ic4*4+2)*HW4];
        float4 a3 = ap[(ic4*4+3)*HW4];
        acc.x += w.x*a0.x + w.y*a1.x + w.z*a2v.x + w.w*a3.x;
        acc.y += w.x*a0.y + w.y*a1.y + w.z*a2v.y + w.w*a3.y;
        acc.z += w.x*a0.z + w.y*a1.z + w.z*a2v.z + w.w*a3.z;
        acc.w += w.x*a0.w + w.y*a1.w + w.z*a2v.w + w.w*a3.w;
    }
    const float4 xv = ((const float4*)x)[t];
    float4 r;
    r.x = xv.x*acc.x; r.y = xv.y*acc.y; r.z = xv.z*acc.z; r.w = xv.w*acc.w;
    ((float4*)out)[t] = r;
}

extern "C" void kernel_launch(void* const* d_in, const int* in_sizes, int n_in,
                              void* d_out, int out_size, void* d_ws, size_t ws_size,
                              hipStream_t stream) {
    const float* x      = (const float*)d_in[0];
    const float* off_w1 = (const float*)d_in[1];
    const float* off_b1 = (const float*)d_in[2];
    const float* dw_w1  = (const float*)d_in[3];
    const float* off_w2 = (const float*)d_in[4];
    const float* off_b2 = (const float*)d_in[5];
    const float* dw_w2  = (const float*)d_in[6];
    const float* pw_w   = (const float*)d_in[7];
    const float* pw_b   = (const float*)d_in[8];
    float* out = (float*)d_out;

    const size_t nF    = (size_t)BB*CC*HW;
    const size_t attnB = nF*sizeof(float);
    const size_t off2B = (size_t)BB*98*HW*sizeof(float);   // fallback layout
    const size_t offTB = (size_t)BB*HW*112*sizeof(float);  // transposed offsets
    const size_t chB   = (size_t)BB*HW*64*sizeof(u16);
    char* ws = (char*)d_ws;

    const int n    = (int)nF;
    const int dbl  = n/64;
    const int pbl  = (n/4 + 255)/256;
    dim3 cblk(64,4);
    dim3 rgrd1(BB*(50/5), HH/4);
    dim3 rgrd2(BB*(98/7), HH/4);
    dim3 cgrd1(TGRID, 2);                    // conv1: 64 n / 32 per block
    dim3 cgrd2(TGRID, 4);                    // conv2: 128 n / 32 per block
    const int dgrid = BB*HW/8;               // 1568 (8 pixels per block)

    const size_t oOFF  = 0;
    const size_t oXT   = oOFF + offTB;
    const size_t oA1T  = oXT  + chB;
    const size_t oA2T  = oA1T + chB;
    const size_t oW1   = oA2T + chB;
    const size_t oW2   = oW1  + (size_t)R1*2;
    const size_t oPWT  = oW2  + (size_t)R2*2;
    const size_t oDW1  = oPWT + (size_t)R3*2;
    const size_t oDW2  = oDW1 + (size_t)R4*4;
    const size_t TOT   = oDW2 + (size_t)R5*4;   // ~11.47 MB

    if (ws_size >= TOT) {
        float* off_buf = (float*)(ws + oOFF);
        u16*   xT      = (u16*)(ws + oXT);
        u16*   a1T     = (u16*)(ws + oA1T);
        u16*   w2t1    = (u16*)(ws + oW1);
        u16*   w2t2    = (u16*)(ws + oW2);
        u16*   pwT     = (u16*)(ws + oPWT);
        float* dwT1    = (float*)(ws + oDW1);
        float* dwT2    = (float*)(ws + oDW2);

        prep_tr_kernel<<<TGRID + (PREPN+255)/256, 256, 0, stream>>>(
            x, off_w1, off_w2, pw_w, dw_w1, dw_w2,
            xT, w2t1, w2t2, pwT, dwT1, dwT2);

        conv_mfma_lds_kernel<5,1,2,50,64,64,2><<<cgrd1, 256, 0, stream>>>(xT, w2t1, off_b1, off_buf);
        deform_cl_kernel<5,1,2,64><<<dgrid, 256, 0, stream>>>(xT, off_buf, dwT1, a1T);

        conv_mfma_lds_kernel<7,3,9,98,128,112,2><<<cgrd2, 256, 0, stream>>>(a1T, w2t2, off_b2, off_buf);
        deform_pw_kernel<7,3,9,112><<<dgrid, 256, 0, stream>>>(a1T, off_buf, dwT2, pwT, pw_b, x, out);
    } else if (ws_size >= off2B + attnB) {
        float* off_buf = (float*)ws;
        float* attn1   = (float*)d_out;
        float* attn2   = (float*)(ws + off2B);
        off_conv_sg_kernel<5,1,2,50,5><<<rgrd1, cblk, 0, stream>>>(x, off_w1, off_b1, off_buf);
        deform_dw_full_kernel<5,1,2><<<dbl, 64, 0, stream>>>(x, off_buf, dw_w1, attn1);
        off_conv_sg_kernel<7,3,9,98,7><<<rgrd2, cblk, 0, stream>>>(attn1, off_w2, off_b2, off_buf);
        deform_dw_full_kernel<7,3,9><<<dbl, 64, 0, stream>>>(attn1, off_buf, dw_w2, attn2);
        pw_mul_kernel<<<pbl, 256, 0, stream>>>(x, attn2, pw_w, pw_b, out);
    } else {
        float* attn1 = (float*)d_out;
        float* attn2 = (float*)ws;
        float* off1  = (float*)ws;
        off_conv_sg_kernel<5,1,2,50,5><<<rgrd1, cblk, 0, stream>>>(x, off_w1, off_b1, off1);
        deform_dw_full_kernel<5,1,2><<<dbl, 64, 0, stream>>>(x, off1, dw_w1, attn1);
        float* off2 = (float*)(ws + attnB);
        off_conv_sg_kernel<7,3,9,98,7><<<rgrd2, cblk, 0, stream>>>(attn1, off_w2, off_b2, off2);
        deform_dw_full_kernel<7,3,9><<<dbl, 64, 0, stream>>>(attn1, off2, dw_w2, attn2);
        pw_mul_kernel<<<pbl, 256, 0, stream>>>(x, attn2, pw_w, pw_b, out);
    }
}

// Round 12
// 152.673 us; speedup vs baseline: 1.4015x; 1.0033x over previous
//
#include <hip/hip_runtime.h>

// Problem constants (from reference setup_inputs)
#define BB 4
#define CC 64
#define HH 56
#define WW 56
#define HW (HH*WW)

typedef unsigned short u16;
typedef unsigned int u32;
typedef __attribute__((ext_vector_type(8))) short bf16x8;
typedef __attribute__((ext_vector_type(4))) float f32x4;

__device__ __forceinline__ u16 f2bf(float f) {
    union { float f; unsigned u; } c; c.f = f;
    unsigned u = c.u;
    u = (u + 0x7FFFu + ((u >> 16) & 1u)) >> 16;   // RNE
    return (u16)u;
}
__device__ __forceinline__ float lo_f(u32 u) {   // bf16 pair -> lo fp32
    union { unsigned u; float f; } c; c.u = u << 16; return c.f;
}
__device__ __forceinline__ float hi_f(u32 u) {   // bf16 pair -> hi fp32
    union { unsigned u; float f; } c; c.u = u & 0xffff0000u; return c.f;
}

// ---------------------------------------------------------------------------
// Fused prep + input transpose in ONE launch (R5 baseline).
// ---------------------------------------------------------------------------
#define R1 102400
#define R2 401408
#define R3 4096
#define R4 1600
#define R5 3136
#define TGRID (BB*(HW/64))          // 196
#define PREPN (R1+R2+R3+R4+R5)
__global__ __launch_bounds__(256)
void prep_tr_kernel(const float* __restrict__ x,
                    const float* __restrict__ ow1, const float* __restrict__ ow2,
                    const float* __restrict__ pw,  const float* __restrict__ dw1,
                    const float* __restrict__ dw2,
                    u16* __restrict__ xT,
                    u16* __restrict__ w2t1, u16* __restrict__ w2t2,
                    u16* __restrict__ pwT, float* __restrict__ dwT1,
                    float* __restrict__ dwT2) {
    __shared__ u16 tile[64][72];
    const int t = threadIdx.x;
    if (blockIdx.x < TGRID) {
        const int blk = blockIdx.x;
        const int b   = blk / (HW/64);
        const int p0  = (blk % (HW/64))*64;
        const int px  = t & 63, icq = t >> 6;
        const float* ip = x + ((size_t)b*CC + icq*16)*HW + p0 + px;
        #pragma unroll
        for (int i = 0; i < 16; ++i)
            tile[px][icq*16 + i] = f2bf(ip[(size_t)i*HW]);
        __syncthreads();
        const int px2 = t >> 2, g = t & 3;
        u16* op = xT + ((size_t)b*HW + p0 + px2)*64 + g*16;
        const uint4* s = (const uint4*)&tile[px2][g*16];
        ((uint4*)op)[0] = s[0];
        ((uint4*)op)[1] = s[1];
        return;
    }
    const int i = (blockIdx.x - TGRID)*256 + t;
    if (i < R1) {
        const int ic = i & 63, n = (i >> 6) & 63, tap = i >> 12;
        w2t1[i] = f2bf((n < 50) ? ow1[((size_t)n*64 + ic)*25 + tap] : 0.f);
    } else if (i < R1+R2) {
        const int j = i - R1;
        const int ic = j & 63, n = (j >> 6) & 127, tap = j >> 13;
        w2t2[j] = f2bf((n < 98) ? ow2[((size_t)n*64 + ic)*49 + tap] : 0.f);
    } else if (i < R1+R2+R3) {
        const int j = i - (R1+R2);
        pwT[j] = f2bf(pw[j]);
    } else if (i < R1+R2+R3+R4) {
        const int j = i - (R1+R2+R3);
        const int c = j & 63, k = j >> 6;
        dwT1[j] = dw1[c*25 + k];
    } else if (i < R1+R2+R3+R4+R5) {
        const int j = i - (R1+R2+R3+R4);
        const int c = j & 63, k = j >> 6;
        dwT2[j] = dw2[c*49 + k];
    }
}

__device__ __forceinline__ uint4 selz(bool v, uint4 a) {
    const uint4 z = make_uint4(0,0,0,0);
    return v ? a : z;
}

// ---------------------------------------------------------------------------
// LDS-staged MFMA implicit-GEMM conv (exact R5 form, measured-best total).
// NTW=2, transposed output (B,HW,NPAD) fp32.
// ---------------------------------------------------------------------------
template<int K, int DIL, int PAD, int COUT, int NP, int NPAD, int NTW>
__global__ __launch_bounds__(256, 4)
void conv_mfma_lds_kernel(const u16* __restrict__ xT, const u16* __restrict__ w2t,
                          const float* __restrict__ bias, float* __restrict__ out) {
    constexpr int KK = K*K;
    constexpr int BROWS = 16*NTW;
    __shared__ u16 Ab[2][64*64];
    __shared__ u16 Bb[2][BROWS*64];

    const int nm   = HW/64;                       // 49
    const int b    = blockIdx.x / nm;
    const int p0   = (blockIdx.x % nm)*64;
    const int nt0  = blockIdx.y;
    const int t    = threadIdx.x;
    const int wave = t >> 6;
    const int lane = t & 63;

    const int spx = t >> 3;                       // 0..31
    const int sc  = t & 7;                        // chunk 0..7
    const int pA  = p0 + spx;
    const int pB  = p0 + spx + 32;
    const int pyA = pA / WW, pxA = pA % WW;
    const int pyB = pB / WW, pxB = pB % WW;
    const u16* xb = xT + (size_t)b*HW*64;
    const int sslotA = ((sc + spx) & 7)*8;
    const int bn  = t >> 3;                       // 0..31
    const int bslot = ((sc + bn) & 7)*8;
    const u16* wbase = w2t + (size_t)nt0*BROWS*64;

    const int r = lane & 15, quad = lane >> 4;
    const int mloc = wave*16 + r;
    const int arow = mloc*64;
    const int a0s = ((quad     + mloc) & 7)*8;
    const int a1s = ((quad + 4 + mloc) & 7)*8;
    const int b0s = ((quad     + r) & 7)*8;
    const int b1s = ((quad + 4 + r) & 7)*8;

    f32x4 acc[NTW];
    #pragma unroll
    for (int h = 0; h < NTW; ++h) acc[h] = (f32x4){0.f,0.f,0.f,0.f};
    const uint4 z4 = make_uint4(0,0,0,0);

    auto LD = [&](int tap, uint4& a0, uint4& a1, bool& va, bool& vb, uint4& bb) {
        const int dyy = (tap/K)*DIL - PAD;
        const int dxx = (tap%K)*DIL - PAD;
        const int off = dyy*WW + dxx;
        {
            const int yy = pyA + dyy, xx = pxA + dxx;
            va = ((unsigned)yy < (unsigned)HH) && ((unsigned)xx < (unsigned)WW);
            a0 = *(const uint4*)(xb + (size_t)(va ? (pA + off) : 0)*64 + sc*8);
        }
        {
            const int yy = pyB + dyy, xx = pxB + dxx;
            vb = ((unsigned)yy < (unsigned)HH) && ((unsigned)xx < (unsigned)WW);
            a1 = *(const uint4*)(xb + (size_t)(vb ? (pB + off) : 0)*64 + sc*8);
        }
        if (BROWS == 32 || bn < BROWS)
            bb = *(const uint4*)(wbase + ((size_t)tap*NP + bn)*64 + sc*8);
    };

    uint4 rA0 = z4, rA1 = z4, rB = z4;
    bool v0 = false, v1 = false;
    LD(0, rA0, rA1, v0, v1, rB);

    #pragma unroll
    for (int tap = 0; tap < KK; ++tap) {
        uint4 nA0 = z4, nA1 = z4, nB = z4;
        bool nv0 = false, nv1 = false;
        if (tap + 1 < KK) LD(tap + 1, nA0, nA1, nv0, nv1, nB);

        u16* A  = &Ab[tap & 1][0];
        u16* Bq = &Bb[tap & 1][0];
        *(uint4*)(A + spx*64      + sslotA) = selz(v0, rA0);
        *(uint4*)(A + (spx+32)*64 + sslotA) = selz(v1, rA1);
        if (BROWS == 32 || bn < BROWS) *(uint4*)(Bq + bn*64 + bslot) = rB;
        __syncthreads();

        const bf16x8 av0 = *(const bf16x8*)(A + arow + a0s);
        const bf16x8 av1 = *(const bf16x8*)(A + arow + a1s);
        #pragma unroll
        for (int h = 0; h < NTW; ++h) {
            const int brow = (h*16 + r)*64;
            const bf16x8 bv0 = *(const bf16x8*)(Bq + brow + b0s);
            const bf16x8 bv1 = *(const bf16x8*)(Bq + brow + b1s);
            acc[h] = __builtin_amdgcn_mfma_f32_16x16x32_bf16(av0, bv0, acc[h], 0, 0, 0);
            acc[h] = __builtin_amdgcn_mfma_f32_16x16x32_bf16(av1, bv1, acc[h], 0, 0, 0);
        }

        rA0 = nA0; rA1 = nA1; rB = nB; v0 = nv0; v1 = nv1;
    }

    #pragma unroll
    for (int h = 0; h < NTW; ++h) {
        const int n = nt0*BROWS + h*16 + r;
        if (n < COUT) {
            const float bv = bias[n];
            float* op = out + ((size_t)b*HW + p0 + wave*16 + quad*4)*NPAD + n;
            #pragma unroll
            for (int r2 = 0; r2 < 4; ++r2) op[(size_t)r2*NPAD] = acc[h][r2] + bv;
        }
    }
}

// ---------------------------------------------------------------------------
// Phase-1 item: bilinear weights + clamped byte addresses for one (pix, k).
// Shared by both deform kernels; math identical to all prior rounds.
// ---------------------------------------------------------------------------
template<int K, int DIL, int PAD>
__device__ __forceinline__ void deform_item(int h, int w, int k, float dy, float dx,
                                            float4* swtp, int4* satp) {
    const float py = (float)(h + (k/K)*DIL - PAD) + dy;
    const float px = (float)(w + (k%K)*DIL - PAD) + dx;
    const float y0f = floorf(py), x0f = floorf(px);
    const float wy1 = py - y0f,  wx1 = px - x0f;
    const float wy0 = 1.f - wy1, wx0 = 1.f - wx1;
    const int y0 = (int)y0f, x0 = (int)x0f;

    const int y0c = min(max(y0,   0), HH-1);
    const int y1c = min(max(y0+1, 0), HH-1);
    const int x0c = min(max(x0,   0), WW-1);
    const int x1c = min(max(x0+1, 0), WW-1);
    const float gy0 = wy0 * ((y0   >= 0 && y0   < HH) ? 1.f : 0.f);
    const float gy1 = wy1 * ((y0+1 >= 0 && y0+1 < HH) ? 1.f : 0.f);
    const float gx0 = wx0 * ((x0   >= 0 && x0   < WW) ? 1.f : 0.f);
    const float gx1 = wx1 * ((x0+1 >= 0 && x0+1 < WW) ? 1.f : 0.f);

    *swtp = make_float4(gy0*gx0, gy0*gx1, gy1*gx0, gy1*gx1);
    const int r0 = y0c*WW, r1 = y1c*WW;
    *satp = make_int4((r0 + x0c) << 7, (r0 + x1c) << 7,
                      (r1 + x0c) << 7, (r1 + x1c) << 7);
}

// ---------------------------------------------------------------------------
// Two-phase deform, 2 channels/lane, R10 deepened software pipeline.
// PHASE-1 NOW COALESCED: one float4 per lane = (dy,dx) for two consecutive
// taps of one pixel (224 resp. 128 x 16B loads per block vs 784 scattered
// scalars on the largest input stream). Item math / swt / sat contents and
// the tap loop are bit-identical to R11. Used for deform1 (K=5) -> a1T.
// ---------------------------------------------------------------------------
template<int K, int DIL, int PAD, int NPAD>
__global__ __launch_bounds__(256)
void deform_cl_kernel(const u16* __restrict__ inT, const float* __restrict__ offT,
                      const float* __restrict__ dwT, u16* __restrict__ outT) {
    constexpr int KK = K*K;
    constexpr int CPX = NPAD/4;                   // float4 per pixel row
    __shared__ float4 swt[8][KK];
    __shared__ int4   sat[8][KK];
    __shared__ float  sdw[KK*64];

    const int t = threadIdx.x;
    const int nb8 = (BB*HW/8) >> 3;               // 196
    const int blk0 = blockIdx.x;
    const int blk = (blk0 & 7)*nb8 + (blk0 >> 3); // XCD-contiguous pixels
    const int p0 = blk*8;
    const int b  = p0 / HW;                       // 8 | HW -> same batch
    const int pl0 = p0 - b*HW;

    for (int i = t; i < KK*64; i += 256) sdw[i] = dwT[i];

    for (int j = t; j < 8*CPX; j += 256) {
        const int pix = j / CPX, q = j - pix*CPX;
        const int pl  = pl0 + pix;
        const int h = pl / WW, w = pl % WW;
        const float4 ov = *(const float4*)(offT + ((size_t)b*HW + pl)*NPAD + q*4);
        const int k0 = q*2;
        if (k0     < KK) deform_item<K,DIL,PAD>(h, w, k0,     ov.x, ov.y, &swt[pix][k0],   &sat[pix][k0]);
        if (k0 + 1 < KK) deform_item<K,DIL,PAD>(h, w, k0 + 1, ov.z, ov.w, &swt[pix][k0+1], &sat[pix][k0+1]);
    }
    __syncthreads();

    const int wave = t >> 6, lane = t & 63;
    const int pixl = 2*wave + (lane >> 5);        // 0..7 (half-wave = pixel)
    const int chp  = lane & 31;                   // channel pair 0..31
    const char* ib = (const char*)(inT + (size_t)b*HW*64) + chp*4;

    float accx = 0.f, accy = 0.f;

    int4   av[4];
    float4 wv[2];
    float2 dv[2];
    u32 c00[3], c01[3], c10[3], c11[3];

    av[0] = sat[pixl][0];
    if (KK > 1) av[1] = sat[pixl][1];
    if (KK > 2) av[2] = sat[pixl][2];
    wv[0] = swt[pixl][0];
    dv[0] = *(const float2*)&sdw[2*chp];
    c00[0] = *(const u32*)(ib + av[0].x);
    c01[0] = *(const u32*)(ib + av[0].y);
    c10[0] = *(const u32*)(ib + av[0].z);
    c11[0] = *(const u32*)(ib + av[0].w);
    if (KK > 1) {
        c00[1] = *(const u32*)(ib + av[1].x);
        c01[1] = *(const u32*)(ib + av[1].y);
        c10[1] = *(const u32*)(ib + av[1].z);
        c11[1] = *(const u32*)(ib + av[1].w);
    }

    #pragma unroll
    for (int k = 0; k < KK; ++k) {
        if (k + 3 < KK) av[(k+3)&3] = sat[pixl][k+3];
        if (k + 2 < KK) {
            const int4 a = av[(k+2)&3];
            c00[(k+2)%3] = *(const u32*)(ib + a.x);
            c01[(k+2)%3] = *(const u32*)(ib + a.y);
            c10[(k+2)%3] = *(const u32*)(ib + a.z);
            c11[(k+2)%3] = *(const u32*)(ib + a.w);
        }
        if (k + 1 < KK) {
            wv[(k+1)&1] = swt[pixl][k+1];
            dv[(k+1)&1] = *(const float2*)&sdw[(k+1)*64 + 2*chp];
        }
        const float4 w = wv[k&1];
        const u32 u00 = c00[k%3], u01 = c01[k%3], u10 = c10[k%3], u11 = c11[k%3];
        const float sx = lo_f(u00)*w.x + lo_f(u01)*w.y + lo_f(u10)*w.z + lo_f(u11)*w.w;
        const float sy = hi_f(u00)*w.x + hi_f(u01)*w.y + hi_f(u10)*w.z + hi_f(u11)*w.w;
        const float2 d = dv[k&1];
        accx += sx * d.x;
        accy += sy * d.y;
    }

    const u32 o = (u32)f2bf(accx) | ((u32)f2bf(accy) << 16);
    *(u32*)((char*)outT + (size_t)(p0 + pixl)*128 + chp*4) = o;
}

// ---------------------------------------------------------------------------
// FUSED deform2 + pointwise + residual multiply (R11 structure, phase-1
// coalesced as above). Epilogue: attn bf16 -> LDS (aliasing dead swt) ->
// pw MFMA (exact fragment sequence) -> out = x*(acc+bias). Bit-identical.
// ---------------------------------------------------------------------------
template<int K, int DIL, int PAD, int NPAD>
__global__ __launch_bounds__(256)
void deform_pw_kernel(const u16* __restrict__ inT, const float* __restrict__ offT,
                      const float* __restrict__ dwT, const u16* __restrict__ pwT,
                      const float* __restrict__ pb, const float* __restrict__ x,
                      float* __restrict__ out) {
    constexpr int KK = K*K;
    constexpr int CPX = NPAD/4;
    __shared__ float4 swt[8][KK];
    __shared__ int4   sat[8][KK];
    __shared__ float  sdw[KK*64];

    const int t = threadIdx.x;
    const int nb8 = (BB*HW/8) >> 3;               // 196
    const int blk0 = blockIdx.x;
    const int blk = (blk0 & 7)*nb8 + (blk0 >> 3); // XCD-contiguous pixels
    const int p0 = blk*8;
    const int b  = p0 / HW;                       // 8 | HW -> same batch
    const int pl0 = p0 - b*HW;

    for (int i = t; i < KK*64; i += 256) sdw[i] = dwT[i];

    for (int j = t; j < 8*CPX; j += 256) {
        const int pix = j / CPX, q = j - pix*CPX;
        const int pl  = pl0 + pix;
        const int h = pl / WW, w = pl % WW;
        const float4 ov = *(const float4*)(offT + ((size_t)b*HW + pl)*NPAD + q*4);
        const int k0 = q*2;
        if (k0     < KK) deform_item<K,DIL,PAD>(h, w, k0,     ov.x, ov.y, &swt[pix][k0],   &sat[pix][k0]);
        if (k0 + 1 < KK) deform_item<K,DIL,PAD>(h, w, k0 + 1, ov.z, ov.w, &swt[pix][k0+1], &sat[pix][k0+1]);
    }
    __syncthreads();

    const int wave = t >> 6, lane = t & 63;
    const int pixl = 2*wave + (lane >> 5);        // 0..7 (half-wave = pixel)
    const int chp  = lane & 31;                   // channel pair 0..31
    const char* ib = (const char*)(inT + (size_t)b*HW*64) + chp*4;

    float accx = 0.f, accy = 0.f;

    int4   av[4];
    float4 wv[2];
    float2 dv[2];
    u32 c00[3], c01[3], c10[3], c11[3];

    av[0] = sat[pixl][0];
    if (KK > 1) av[1] = sat[pixl][1];
    if (KK > 2) av[2] = sat[pixl][2];
    wv[0] = swt[pixl][0];
    dv[0] = *(const float2*)&sdw[2*chp];
    c00[0] = *(const u32*)(ib + av[0].x);
    c01[0] = *(const u32*)(ib + av[0].y);
    c10[0] = *(const u32*)(ib + av[0].z);
    c11[0] = *(const u32*)(ib + av[0].w);
    if (KK > 1) {
        c00[1] = *(const u32*)(ib + av[1].x);
        c01[1] = *(const u32*)(ib + av[1].y);
        c10[1] = *(const u32*)(ib + av[1].z);
        c11[1] = *(const u32*)(ib + av[1].w);
    }

    #pragma unroll
    for (int k = 0; k < KK; ++k) {
        if (k + 3 < KK) av[(k+3)&3] = sat[pixl][k+3];
        if (k + 2 < KK) {
            const int4 a = av[(k+2)&3];
            c00[(k+2)%3] = *(const u32*)(ib + a.x);
            c01[(k+2)%3] = *(const u32*)(ib + a.y);
            c10[(k+2)%3] = *(const u32*)(ib + a.z);
            c11[(k+2)%3] = *(const u32*)(ib + a.w);
        }
        if (k + 1 < KK) {
            wv[(k+1)&1] = swt[pixl][k+1];
            dv[(k+1)&1] = *(const float2*)&sdw[(k+1)*64 + 2*chp];
        }
        const float4 w = wv[k&1];
        const u32 u00 = c00[k%3], u01 = c01[k%3], u10 = c10[k%3], u11 = c11[k%3];
        const float sx = lo_f(u00)*w.x + lo_f(u01)*w.y + lo_f(u10)*w.z + lo_f(u11)*w.w;
        const float sy = hi_f(u00)*w.x + hi_f(u01)*w.y + hi_f(u10)*w.z + hi_f(u11)*w.w;
        const float2 d = dv[k&1];
        accx += sx * d.x;
        accy += sy * d.y;
    }

    // ---- fused pw epilogue ----
    __syncthreads();                              // all waves done reading swt/sat
    u16* att = (u16*)&swt[0][0];                  // alias dead swt buffer (2KB used)
    const u32 o = (u32)f2bf(accx) | ((u32)f2bf(accy) << 16);
    *(u32*)((char*)att + pixl*128 + chp*4) = o;   // att[pix][ch] bf16, rows 0..7
    __syncthreads();

    const int r = lane & 15, quad = lane >> 4;
    f32x4 pacc = (f32x4){0.f,0.f,0.f,0.f};
    #pragma unroll
    for (int ks = 0; ks < 2; ++ks) {
        const bf16x8 pav = *(const bf16x8*)(att + r*64 + ks*32 + quad*8);
        const bf16x8 pbv = *(const bf16x8*)(pwT + ((size_t)(wave*16 + r))*64 + ks*32 + quad*8);
        pacc = __builtin_amdgcn_mfma_f32_16x16x32_bf16(pav, pbv, pacc, 0, 0, 0);
    }
    if (quad < 2) {                               // C rows = pixels quad*4+r2 (0..7 valid)
        const int n = wave*16 + r;
        const float bvb = pb[n];
        const size_t base = ((size_t)b*CC + n)*HW + pl0 + quad*4;
        #pragma unroll
        for (int r2 = 0; r2 < 4; ++r2)
            out[base + r2] = x[base + r2] * (pacc[r2] + bvb);
    }
}

// ======================= fallback fp32 kernels (low ws) =====================
template<int K, int DIL, int PAD, int COUT, int OCB>
__global__ __launch_bounds__(256)
void off_conv_sg_kernel(const float* __restrict__ in, const float* __restrict__ wgt,
                        const float* __restrict__ bias, float* __restrict__ out) {
    constexpr int KK = K*K;
    const int nOB = COUT / OCB;
    const int b   = blockIdx.x / nOB;
    const int oc0 = (blockIdx.x % nOB) * OCB;
    const int x   = threadIdx.x;
    const int h   = blockIdx.y*4 + threadIdx.y;

    float acc[OCB];
    #pragma unroll
    for (int o = 0; o < OCB; ++o) acc[o] = bias[oc0+o];

    const float* inb = in + (size_t)b*CC*HW;
    const float* wb  = wgt + (size_t)oc0*CC*KK;

    for (int ic = 0; ic < CC; ++ic) {
        const float* inp = inb + ic*HW;
        const float* wp  = wb + ic*KK;
        #pragma unroll
        for (int ky = 0; ky < K; ++ky) {
            const int  y  = h + ky*DIL - PAD;
            const bool yv = (y >= 0) && (y < HH);
            const int  yc = yv ? y : 0;
            const float* row = inp + yc*WW;
            #pragma unroll
            for (int kx = 0; kx < K; ++kx) {
                const int  xx = x + kx*DIL - PAD;
                const bool v  = yv && (xx >= 0) && (xx < WW);
                const int  xc = (xx < 0) ? 0 : ((xx >= WW) ? (WW-1) : xx);
                float val = row[xc];
                val = v ? val : 0.f;
                const int t = ky*K + kx;
                #pragma unroll
                for (int o = 0; o < OCB; ++o)
                    acc[o] += wp[(size_t)o*CC*KK + t] * val;
            }
        }
    }

    if (x >= WW) return;
    #pragma unroll
    for (int o = 0; o < OCB; ++o)
        out[((size_t)b*COUT + oc0 + o)*HW + h*WW + x] = acc[o];
}

template<int K, int DIL, int PAD>
__global__ __launch_bounds__(64)
void deform_dw_full_kernel(const float* __restrict__ in, const float* __restrict__ off,
                           const float* __restrict__ dw, float* __restrict__ out) {
    constexpr int KK = K*K;
    const int idx = blockIdx.x*64 + threadIdx.x;
    const int x = idx % WW;
    const int h = (idx / WW) % HH;
    const int c = (idx / HW) % CC;
    const int b = idx / (CC*HW);

    const float* inp  = in  + ((size_t)b*CC + c)*HW;
    const float* offp = off + (size_t)b*(2*KK)*HW + h*WW + x;
    const float* dwp  = dw  + c*KK;

    float acc = 0.f;
    #pragma unroll 7
    for (int k = 0; k < KK; ++k) {
        const float dy = offp[(2*k  )*HW];
        const float dx = offp[(2*k+1)*HW];
        const float py = (float)(h + (k/K)*DIL - PAD) + dy;
        const float px = (float)(x + (k%K)*DIL - PAD) + dx;
        const float y0f = floorf(py), x0f = floorf(px);
        const float wy1 = py - y0f,  wx1 = px - x0f;
        const float wy0 = 1.f - wy1, wx0 = 1.f - wx1;
        const int y0 = (int)y0f, x0 = (int)x0f;

        const int y0c = min(max(y0,   0), HH-1);
        const int y1c = min(max(y0+1, 0), HH-1);
        const int x0c = min(max(x0,   0), WW-1);
        const int x1c = min(max(x0+1, 0), WW-1);
        const float my0 = (y0   >= 0 && y0   < HH) ? 1.f : 0.f;
        const float my1 = (y0+1 >= 0 && y0+1 < HH) ? 1.f : 0.f;
        const float mx0 = (x0   >= 0 && x0   < WW) ? 1.f : 0.f;
        const float mx1 = (x0+1 >= 0 && x0+1 < WW) ? 1.f : 0.f;

        const float v00 = inp[y0c*WW + x0c];
        const float v01 = inp[y0c*WW + x1c];
        const float v10 = inp[y1c*WW + x0c];
        const float v11 = inp[y1c*WW + x1c];

        const float gx0 = wx0*mx0, gx1 = wx1*mx1;
        const float s = (v00*gx0 + v01*gx1) * (wy0*my0)
                      + (v10*gx0 + v11*gx1) * (wy1*my1);
        acc += s * dwp[k];
    }
    out[idx] = acc;
}

__global__ __launch_bounds__(256)
void pw_mul_kernel(const float* __restrict__ x, const float* __restrict__ a2,
                   const float* __restrict__ pw, const float* __restrict__ pb,
                   float* __restrict__ out) {
    constexpr int HW4 = HW/4;
    const int t = blockIdx.x*256 + threadIdx.x;
    if (t >= BB*CC*HW4) return;
    const int sp4 = t % HW4;
    const int oc  = (t / HW4) % CC;
    const int b   = t / (CC*HW4);

    const float4* ap = (const float4*)(a2 + (size_t)b*CC*HW) + sp4;
    const float4* wp4 = (const float4*)(pw + oc*CC);
    const float pbv = pb[oc];
    float4 acc = make_float4(pbv, pbv, pbv, pbv);
    #pragma unroll 4
    for (int ic4 = 0; ic4 < CC/4; ++ic4) {
        const float4 w = wp4[ic4];
        float4 a0 = ap[(ic4*4+0)*HW4];
        float4 a1 = ap[(ic4*4+1)*HW4];
        float4 a2v = ap[(ic4*4+2)*HW4];
        float4 a3 = ap[(ic4*4+3)*HW4];
        acc.x += w.x*a0.x + w.y*a1.x + w.z*a2v.x + w.w*a3.x;
        acc.y += w.x*a0.y + w.y*a1.y + w.z*a2v.y + w.w*a3.y;
        acc.z += w.x*a0.z + w.y*a1.z + w.z*a2v.z + w.w*a3.z;
        acc.w += w.x*a0.w + w.y*a1.w + w.z*a2v.w + w.w*a3.w;
    }
    const float4 xv = ((const float4*)x)[t];
    float4 r;
    r.x = xv.x*acc.x; r.y = xv.y*acc.y; r.z = xv.z*acc.z; r.w = xv.w*acc.w;
    ((float4*)out)[t] = r;
}

extern "C" void kernel_launch(void* const* d_in, const int* in_sizes, int n_in,
                              void* d_out, int out_size, void* d_ws, size_t ws_size,
                              hipStream_t stream) {
    const float* x      = (const float*)d_in[0];
    const float* off_w1 = (const float*)d_in[1];
    const float* off_b1 = (const float*)d_in[2];
    const float* dw_w1  = (const float*)d_in[3];
    const float* off_w2 = (const float*)d_in[4];
    const float* off_b2 = (const float*)d_in[5];
    const float* dw_w2  = (const float*)d_in[6];
    const float* pw_w   = (const float*)d_in[7];
    const float* pw_b   = (const float*)d_in[8];
    float* out = (float*)d_out;

    const size_t nF    = (size_t)BB*CC*HW;
    const size_t attnB = nF*sizeof(float);
    const size_t off2B = (size_t)BB*98*HW*sizeof(float);   // fallback layout
    const size_t offTB = (size_t)BB*HW*112*sizeof(float);  // transposed offsets
    const size_t chB   = (size_t)BB*HW*64*sizeof(u16);
    char* ws = (char*)d_ws;

    const int n    = (int)nF;
    const int dbl  = n/64;
    const int pbl  = (n/4 + 255)/256;
    dim3 cblk(64,4);
    dim3 rgrd1(BB*(50/5), HH/4);
    dim3 rgrd2(BB*(98/7), HH/4);
    dim3 cgrd1(TGRID, 2);                    // conv1: 64 n / 32 per block
    dim3 cgrd2(TGRID, 4);                    // conv2: 128 n / 32 per block
    const int dgrid = BB*HW/8;               // 1568 (8 pixels per block)

    const size_t oOFF  = 0;
    const size_t oXT   = oOFF + offTB;
    const size_t oA1T  = oXT  + chB;
    const size_t oA2T  = oA1T + chB;
    const size_t oW1   = oA2T + chB;
    const size_t oW2   = oW1  + (size_t)R1*2;
    const size_t oPWT  = oW2  + (size_t)R2*2;
    const size_t oDW1  = oPWT + (size_t)R3*2;
    const size_t oDW2  = oDW1 + (size_t)R4*4;
    const size_t TOT   = oDW2 + (size_t)R5*4;   // ~11.47 MB

    if (ws_size >= TOT) {
        float* off_buf = (float*)(ws + oOFF);
        u16*   xT      = (u16*)(ws + oXT);
        u16*   a1T     = (u16*)(ws + oA1T);
        u16*   w2t1    = (u16*)(ws + oW1);
        u16*   w2t2    = (u16*)(ws + oW2);
        u16*   pwT     = (u16*)(ws + oPWT);
        float* dwT1    = (float*)(ws + oDW1);
        float* dwT2    = (float*)(ws + oDW2);

        prep_tr_kernel<<<TGRID + (PREPN+255)/256, 256, 0, stream>>>(
            x, off_w1, off_w2, pw_w, dw_w1, dw_w2,
            xT, w2t1, w2t2, pwT, dwT1, dwT2);

        conv_mfma_lds_kernel<5,1,2,50,64,64,2><<<cgrd1, 256, 0, stream>>>(xT, w2t1, off_b1, off_buf);
        deform_cl_kernel<5,1,2,64><<<dgrid, 256, 0, stream>>>(xT, off_buf, dwT1, a1T);

        conv_mfma_lds_kernel<7,3,9,98,128,112,2><<<cgrd2, 256, 0, stream>>>(a1T, w2t2, off_b2, off_buf);
        deform_pw_kernel<7,3,9,112><<<dgrid, 256, 0, stream>>>(a1T, off_buf, dwT2, pwT, pw_b, x, out);
    } else if (ws_size >= off2B + attnB) {
        float* off_buf = (float*)ws;
        float* attn1   = (float*)d_out;
        float* attn2   = (float*)(ws + off2B);
        off_conv_sg_kernel<5,1,2,50,5><<<rgrd1, cblk, 0, stream>>>(x, off_w1, off_b1, off_buf);
        deform_dw_full_kernel<5,1,2><<<dbl, 64, 0, stream>>>(x, off_buf, dw_w1, attn1);
        off_conv_sg_kernel<7,3,9,98,7><<<rgrd2, cblk, 0, stream>>>(attn1, off_w2, off_b2, off_buf);
        deform_dw_full_kernel<7,3,9><<<dbl, 64, 0, stream>>>(attn1, off_buf, dw_w2, attn2);
        pw_mul_kernel<<<pbl, 256, 0, stream>>>(x, attn2, pw_w, pw_b, out);
    } else {
        float* attn1 = (float*)d_out;
        float* attn2 = (float*)ws;
        float* off1  = (float*)ws;
        off_conv_sg_kernel<5,1,2,50,5><<<rgrd1, cblk, 0, stream>>>(x, off_w1, off_b1, off1);
        deform_dw_full_kernel<5,1,2><<<dbl, 64, 0, stream>>>(x, off1, dw_w1, attn1);
        float* off2 = (float*)(ws + attnB);
        off_conv_sg_kernel<7,3,9,98,7><<<rgrd2, cblk, 0, stream>>>(attn1, off_w2, off_b2, off2);
        deform_dw_full_kernel<7,3,9><<<dbl, 64, 0, stream>>>(attn1, off2, dw_w2, attn2);
        pw_mul_kernel<<<pbl, 256, 0, stream>>>(x, attn2, pw_w, pw_b, out);
    }
}